// Round 1
// baseline (515.284 us; speedup 1.0000x reference)
//
#include <hip/hip_runtime.h>
#include <hip/hip_bf16.h>
#include <cstdint>

// Fixed problem shape (EfficientAttention): n=8, C=512, W=8192, H=8, hk=hv=64
#define NB 8
#define CD 512
#define WD 8192
#define NH 8

typedef __bf16 bf16x8 __attribute__((ext_vector_type(8)));
typedef float  f32x4  __attribute__((ext_vector_type(4)));
typedef float  f32x16 __attribute__((ext_vector_type(16)));

// async global->LDS, 16B per lane (wave-uniform base + lane*16 dest).
__device__ __forceinline__ void gload_lds16(const __bf16* g, __bf16* l) {
  __builtin_amdgcn_global_load_lds((const __attribute__((address_space(1))) void*)g,
                                   (__attribute__((address_space(3))) void*)l,
                                   16, 0, 0);
}

// ---------------------------------------------------------------------------
// prep_x: x[n][512][8192] fp32  ->  xT[n][8192][512] bf16 (LDS tile transpose)
// ---------------------------------------------------------------------------
__global__ void __launch_bounds__(256) prep_x_kernel(const float* __restrict__ x,
                                                     __bf16* __restrict__ xT) {
  __shared__ float tile[64][65];
  const int n = blockIdx.z, cb = blockIdx.y * 64, wb = blockIdx.x * 64;
  const int t = threadIdx.x;
  const int t63 = t & 63, tg = t >> 6;
  const float* xp = x + ((size_t)n * CD + cb) * WD + wb;
#pragma unroll
  for (int i = 0; i < 16; i++) {
    const int cc = tg * 16 + i;
    tile[cc][t63] = xp[(size_t)cc * WD + t63];
  }
  __syncthreads();
  __bf16* op = xT + ((size_t)n * WD + wb) * CD + cb;
#pragma unroll
  for (int i = 0; i < 16; i++) {
    const int ww = tg * 16 + i;
    op[(size_t)ww * CD + t63] = (__bf16)tile[t63][ww];
  }
}

// ---------------------------------------------------------------------------
// prep_w: convert weights to bf16; pack bk|bv into bkv
// ---------------------------------------------------------------------------
__global__ void __launch_bounds__(256) prep_w_kernel(const float* __restrict__ Wk,
                                                     const float* __restrict__ Wq,
                                                     const float* __restrict__ Wv,
                                                     const float* __restrict__ Wr,
                                                     const float* __restrict__ bk,
                                                     const float* __restrict__ bv,
                                                     __bf16* __restrict__ WkvB,
                                                     __bf16* __restrict__ WqB,
                                                     __bf16* __restrict__ WrB,
                                                     float* __restrict__ bkv) {
  const int gid = blockIdx.x * 256 + threadIdx.x;  // 0..262143
  WkvB[gid]          = (__bf16)Wk[gid];
  WkvB[262144 + gid] = (__bf16)Wv[gid];
  WqB[gid]           = (__bf16)Wq[gid];
  WrB[gid]           = (__bf16)Wr[gid];
  if (gid < 512)       bkv[gid] = bk[gid];
  else if (gid < 1024) bkv[gid] = bv[gid - 512];
}

// ---------------------------------------------------------------------------
// Shared LDS staging for the old 128^2 cores: 2048 16B chunks (A:[0,1024)
// B:[1024,2048)). Chunk (row r, kgroup g) of BK=64 slab -> slot r*8+(g^(r&7)).
// ---------------------------------------------------------------------------
#define STAGE_SLAB(Ak, Bk, lds, t)                                          \
  _Pragma("unroll") for (int rnd = 0; rnd < 8; rnd++) {                     \
    const int c = rnd * 256 + (t);                                          \
    const int cc = c & 1023;                                                \
    const int r = cc >> 3;                                                  \
    const int g = (cc & 7) ^ (r & 7);                                       \
    const __bf16* src = ((c >> 10) ? (Bk) : (Ak)) + (size_t)r * 512 + g * 8;\
    gload_lds16(src, (lds) + (size_t)c * 8);                                \
  }

// 16x16x32 core (verified). A[m][k], BT[n][k], K=512, ld=512.
__device__ __forceinline__ void gemm_lds_core(const __bf16* __restrict__ A,
                                              const __bf16* __restrict__ B,
                                              f32x4 (&acc)[4][4], __bf16* lds) {
  const int t = threadIdx.x;
  const int lane = t & 63, wave = t >> 6;
  const int l15 = lane & 15, quad = lane >> 4;
  const int wm = (wave >> 1) << 6, wn = (wave & 1) << 6;
#pragma unroll 1
  for (int kc = 0; kc < 8; kc++) {
    const __bf16* Ak = A + kc * 64;
    const __bf16* Bk = B + kc * 64;
    STAGE_SLAB(Ak, Bk, lds, t)
    __syncthreads();
#pragma unroll
    for (int k0 = 0; k0 < 2; k0++) {
      const int gk = k0 * 4 + quad;
      bf16x8 av[4], bv[4];
#pragma unroll
      for (int i = 0; i < 4; i++) {
        const int r = wm + i * 16 + l15;
        av[i] = *(const bf16x8*)(lds + (size_t)((r << 3) + (gk ^ (r & 7))) * 8);
      }
#pragma unroll
      for (int j = 0; j < 4; j++) {
        const int r = wn + j * 16 + l15;
        bv[j] = *(const bf16x8*)(lds + (size_t)(8192 + (r << 3) + (gk ^ (r & 7))) * 8);
      }
#pragma unroll
      for (int i = 0; i < 4; i++)
#pragma unroll
        for (int j = 0; j < 4; j++)
          acc[i][j] = __builtin_amdgcn_mfma_f32_16x16x32_bf16(av[i], bv[j], acc[i][j], 0, 0, 0);
    }
    __syncthreads();
  }
}

// 32x32x16 core: same staging/swizzle, half the MFMA instruction count.
__device__ __forceinline__ void gemm_lds_core32(const __bf16* __restrict__ A,
                                                const __bf16* __restrict__ B,
                                                f32x16 (&acc)[2][2], __bf16* lds) {
  const int t = threadIdx.x;
  const int lane = t & 63, wave = t >> 6;
  const int l31 = lane & 31, khalf = lane >> 5;
  const int wm = (wave >> 1) << 6, wn = (wave & 1) << 6;
#pragma unroll 1
  for (int kc = 0; kc < 8; kc++) {
    const __bf16* Ak = A + kc * 64;
    const __bf16* Bk = B + kc * 64;
    STAGE_SLAB(Ak, Bk, lds, t)
    __syncthreads();
#pragma unroll
    for (int kk = 0; kk < 4; kk++) {
      const int g = kk * 2 + khalf;
      bf16x8 av[2], bv[2];
#pragma unroll
      for (int i = 0; i < 2; i++) {
        const int r = wm + i * 32 + l31;
        av[i] = *(const bf16x8*)(lds + (size_t)((r << 3) + (g ^ (r & 7))) * 8);
      }
#pragma unroll
      for (int j = 0; j < 2; j++) {
        const int r = wn + j * 32 + l31;
        bv[j] = *(const bf16x8*)(lds + (size_t)(8192 + (r << 3) + (g ^ (r & 7))) * 8);
      }
#pragma unroll
      for (int i = 0; i < 2; i++)
#pragma unroll
        for (int j = 0; j < 2; j++)
          acc[i][j] = __builtin_amdgcn_mfma_f32_32x32x16_bf16(av[i], bv[j], acc[i][j], 0, 0, 0);
    }
    __syncthreads();
  }
}

// ---------------------------------------------------------------------------
// NEW gemm_kv: 8-phase 256x256 tile, BK=64, 8 waves, 128 KiB LDS dbuf,
// counted vmcnt (T3+T4), setprio (T5), chunk-XOR swizzle (T2), XCD swizzle (T1).
//
// LDS: buf0 = slabs 0,2,4,6 ; buf1 = slabs 1,3,5,7 (A 32KB + B 32KB each).
// Chunk (row r<256, kgroup g<8) of a slab -> slot r*8 + (g^(r&7)), 16B slots.
// Iteration i: phases 0-3 consume slab 2i (quadrants (mh,nh)=(0,0)(0,1)(1,0)(1,1)),
// phases 4-7 consume slab 2i+1.  Stage schedule (1 unit = 16KB = 2 loads/thread):
//   ph0: A1(2i+1)  ph1: B1(2i+1)  ph2: A0(2i+2)  ph3: B0(2i+2) +vmcnt(4)
//   ph4: A1(2i+2)  ph5: B1(2i+2)  ph6: A0(2i+3)  ph7: B0(2i+3) +vmcnt(4)
// A-unit u = rows {u*64..+64} u {128+u*64..+64}; B-unit v = 32-row stripes
// with (r>>5)&1 == v.  Every stage->consume lag >= 4 phases; vmcnt(4) at
// ph3/ph7 (allow newest 2 units in flight) guarantees landing.  Write-after-
// read is safe: each unit's last reader drained by that phase's
// lgkmcnt(0)+barrier before the (>=1 phase later) restage of its region.
// ---------------------------------------------------------------------------
__device__ __forceinline__ void stage_chunk(const __bf16* __restrict__ g, __bf16* l, int row0) {
  const int lane = threadIdx.x & 63;
  const int r = row0 + (lane >> 3);
  const int sg = lane & 7;
  const int gk = sg ^ (r & 7);  // pre-swizzled global source, linear LDS dest
  gload_lds16(g + (size_t)r * 512 + gk * 8, l + (((r << 3) + sg) << 3));
}

__device__ __forceinline__ void stage_a_unit(const __bf16* __restrict__ g, __bf16* l, int u) {
  const int w8 = (threadIdx.x >> 6) << 3;
  stage_chunk(g, l, u * 64 + w8);
  stage_chunk(g, l, 128 + u * 64 + w8);
}

__device__ __forceinline__ void stage_b_unit(const __bf16* __restrict__ g, __bf16* l, int v) {
  const int w = threadIdx.x >> 6;
  const int r0 = ((w & 3) << 3) + ((w >> 2) << 6) + (v << 5);
  stage_chunk(g, l, r0);
  stage_chunk(g, l, 128 + r0);
}

#define CKPT(N) asm volatile("s_waitcnt vmcnt(" #N ")" ::: "memory")

#define PHASE(BSEL, MH, NH, STAGE_STMT, CKPT_STMT)                              \
  do {                                                                          \
    const __bf16* lA = lds + (BSEL) * 32768;                                    \
    const __bf16* lB = lds + (BSEL) * 32768 + 16384;                            \
    bf16x8 av[4][2], bv[2][2];                                                  \
    _Pragma("unroll") for (int ks = 0; ks < 2; ks++) {                          \
      const int gko = (ks * 4 + quad) ^ (l15 & 7); /* r&7 == l15&7 here */      \
      _Pragma("unroll") for (int mi = 0; mi < 4; mi++) {                        \
        const int r = wm128 + (MH) * 64 + mi * 16 + l15;                        \
        av[mi][ks] = *(const bf16x8*)(lA + (((r << 3) + gko) << 3));            \
      }                                                                         \
      _Pragma("unroll") for (int nj = 0; nj < 2; nj++) {                        \
        const int r = wn64 + (NH) * 32 + nj * 16 + l15;                         \
        bv[nj][ks] = *(const bf16x8*)(lB + (((r << 3) + gko) << 3));            \
      }                                                                         \
    }                                                                           \
    STAGE_STMT;                                                                 \
    __builtin_amdgcn_s_barrier();                                               \
    asm volatile("s_waitcnt lgkmcnt(0)" ::: "memory");                          \
    __builtin_amdgcn_sched_barrier(0);                                          \
    __builtin_amdgcn_s_setprio(1);                                              \
    _Pragma("unroll") for (int ks = 0; ks < 2; ks++)                            \
      _Pragma("unroll") for (int mi = 0; mi < 4; mi++)                          \
        _Pragma("unroll") for (int nj = 0; nj < 2; nj++)                        \
          acc[(MH) * 4 + mi][(NH) * 2 + nj] =                                   \
              __builtin_amdgcn_mfma_f32_16x16x32_bf16(                          \
                  av[mi][ks], bv[nj][ks], acc[(MH) * 4 + mi][(NH) * 2 + nj],    \
                  0, 0, 0);                                                     \
    __builtin_amdgcn_s_setprio(0);                                              \
    CKPT_STMT;                                                                  \
    __builtin_amdgcn_s_barrier();                                               \
  } while (0)

__global__ void __launch_bounds__(512, 2) gemm_kv_kernel(const __bf16* __restrict__ WkvB,
                                                         const __bf16* __restrict__ xT,
                                                         const float* __restrict__ bkv,
                                                         __bf16* __restrict__ kv) {
  extern __shared__ __bf16 lds[];
  const int t = threadIdx.x;
  const int lane = t & 63;
  const int l15 = lane & 15, quad = lane >> 4;
  const int wave = t >> 6;
  const int wm128 = (wave >> 2) << 7;  // 0 / 128
  const int wn64 = (wave & 3) << 6;    // 0 / 64 / 128 / 192

  // XCD-bijective swizzle over 1024 blocks: each XCD gets a contiguous chunk;
  // m-tile fastest so 4 blocks sharing a 256KB xT panel co-reside per XCD L2.
  const int bid = blockIdx.x;
  const int swz = (bid & 7) * 128 + (bid >> 3);
  const int m0 = (swz & 3) << 8;
  const int w0 = ((swz >> 2) & 31) << 8;
  const int n = swz >> 7;

  const __bf16* Ab = WkvB + (size_t)m0 * 512;
  const __bf16* Bb = xT + ((size_t)n * WD + w0) * 512;

  f32x4 acc[8][4];
#pragma unroll
  for (int i = 0; i < 8; i++)
#pragma unroll
    for (int j = 0; j < 4; j++) acc[i][j] = (f32x4){0.f, 0.f, 0.f, 0.f};

  __bf16* const lA0 = lds;
  __bf16* const lB0 = lds + 16384;
  __bf16* const lA1 = lds + 32768;
  __bf16* const lB1 = lds + 49152;

  // prologue: slab0 fully + slab1 A0,B0  (12 loads/thread), then allow the
  // newest 2 units (slab1's) to stay in flight.
  stage_a_unit(Ab, lA0, 0);
  stage_b_unit(Bb, lB0, 0);
  stage_a_unit(Ab, lA0, 1);
  stage_b_unit(Bb, lB0, 1);
  stage_a_unit(Ab + 64, lA1, 0);
  stage_b_unit(Bb + 64, lB1, 0);
  asm volatile("s_waitcnt vmcnt(4)" ::: "memory");
  __builtin_amdgcn_s_barrier();

#pragma unroll 1
  for (int i = 0; i < 3; i++) {
    const __bf16* As1 = Ab + (2 * i + 1) * 64;
    const __bf16* Bs1 = Bb + (2 * i + 1) * 64;
    const __bf16* As2 = Ab + (2 * i + 2) * 64;
    const __bf16* Bs2 = Bb + (2 * i + 2) * 64;
    const __bf16* As3 = Ab + (2 * i + 3) * 64;
    const __bf16* Bs3 = Bb + (2 * i + 3) * 64;
    PHASE(0, 0, 0, stage_a_unit(As1, lA1, 1), (void)0);
    PHASE(0, 0, 1, stage_b_unit(Bs1, lB1, 1), (void)0);
    PHASE(0, 1, 0, stage_a_unit(As2, lA0, 0), (void)0);
    PHASE(0, 1, 1, stage_b_unit(Bs2, lB0, 0), CKPT(4));
    PHASE(1, 0, 0, stage_a_unit(As2, lA0, 1), (void)0);
    PHASE(1, 0, 1, stage_b_unit(Bs2, lB0, 1), (void)0);
    PHASE(1, 1, 0, stage_a_unit(As3, lA1, 0), (void)0);
    PHASE(1, 1, 1, stage_b_unit(Bs3, lB1, 0), CKPT(4));
  }
  // tail iteration (slabs 6,7): only slab7's A1,B1 remain to stage; drain once.
  PHASE(0, 0, 0, stage_a_unit(Ab + 7 * 64, lA1, 1), (void)0);
  PHASE(0, 0, 1, stage_b_unit(Bb + 7 * 64, lB1, 1), (void)0);
  PHASE(0, 1, 0, (void)0, (void)0);
  PHASE(0, 1, 1, (void)0, CKPT(0));
  PHASE(1, 0, 0, (void)0, (void)0);
  PHASE(1, 0, 1, (void)0, (void)0);
  PHASE(1, 1, 0, (void)0, (void)0);
  PHASE(1, 1, 1, (void)0, (void)0);

  // epilogue: D col=lane&15 (w), row=quad*4+reg (m); bias over m.
#pragma unroll
  for (int MI = 0; MI < 8; MI++)
#pragma unroll
    for (int r = 0; r < 4; r++) {
      const int m = m0 + wm128 + MI * 16 + quad * 4 + r;
      const float bias = bkv[m];
      __bf16* rp = kv + ((size_t)n * 1024 + m) * WD + w0 + wn64 + l15;
#pragma unroll
      for (int j = 0; j < 4; j++) rp[j * 16] = (__bf16)(acc[MI][j][r] + bias);
    }
}

// gemm_qT + fused Q-softmax epilogue.
// qT[n][8192][512] bf16 : queries transposed (w-major), softmaxed per head.
__global__ void __launch_bounds__(256) gemm_qT_kernel(const __bf16* __restrict__ xT,
                                                      const __bf16* __restrict__ WqB,
                                                      const float* __restrict__ bq,
                                                      __bf16* __restrict__ qT) {
  __shared__ __bf16 lds[16384];
  const int n = blockIdx.z, w0 = blockIdx.x * 128, q0 = blockIdx.y * 128;
  f32x4 acc[4][4];
#pragma unroll
  for (int i = 0; i < 4; i++)
#pragma unroll
    for (int j = 0; j < 4; j++) acc[i][j] = (f32x4){0.f, 0.f, 0.f, 0.f};
  gemm_lds_core(xT + ((size_t)n * WD + w0) * 512, WqB + (size_t)q0 * 512, acc, lds);
  const int t = threadIdx.x, lane = t & 63, wave = t >> 6;
  const int l15 = lane & 15, quad = lane >> 4;
  const int wm = (wave >> 1) << 6, wn = (wave & 1) << 6;
  float bqv[4];
#pragma unroll
  for (int j = 0; j < 4; j++) bqv[j] = bq[q0 + wn + j * 16 + l15];
#pragma unroll
  for (int i = 0; i < 4; i++)
#pragma unroll
    for (int r = 0; r < 4; r++) {
      float e[4];
      float s = 0.f;
#pragma unroll
      for (int j = 0; j < 4; j++) {
        e[j] = __expf(acc[i][j][r] + bqv[j]);
        s += e[j];
      }
      s += __shfl_xor(s, 1);
      s += __shfl_xor(s, 2);
      s += __shfl_xor(s, 4);
      s += __shfl_xor(s, 8);
      const float inv = 1.0f / s;
      const int w = w0 + wm + i * 16 + quad * 4 + r;
      __bf16* rp = qT + ((size_t)n * WD + w) * 512 + q0 + wn + l15;
#pragma unroll
      for (int j = 0; j < 4; j++) rp[j * 16] = (__bf16)(e[j] * inv);
    }
}

// final: out[n][512][8192] fp32 = Mf[n] (512x512) @ Qsm + br + x
__global__ void __launch_bounds__(256) gemm_out_kernel(const __bf16* __restrict__ Mf,
                                                       const __bf16* __restrict__ qT,
                                                       const float* __restrict__ br,
                                                       const float* __restrict__ x,
                                                       float* __restrict__ out) {
  __shared__ __bf16 lds[16384];
  const int n = blockIdx.z, c0 = blockIdx.y * 128, w0 = blockIdx.x * 128;
  f32x16 acc[2][2];
#pragma unroll
  for (int i = 0; i < 2; i++)
#pragma unroll
    for (int j = 0; j < 2; j++)
#pragma unroll
      for (int r = 0; r < 16; r++) acc[i][j][r] = 0.f;
  gemm_lds_core32(Mf + ((size_t)n * 512 + c0) * 512, qT + ((size_t)n * WD + w0) * 512, acc, lds);
  const int t = threadIdx.x, lane = t & 63, wave = t >> 6;
  const int l31 = lane & 31, khalf = lane >> 5;
  const int wm = (wave >> 1) << 6, wn = (wave & 1) << 6;
#pragma unroll
  for (int i = 0; i < 2; i++)
#pragma unroll
    for (int reg = 0; reg < 16; reg++) {
      const int row = (reg & 3) + 8 * (reg >> 2) + 4 * khalf;
      const int c = c0 + wm + i * 32 + row;
      const float bias = br[c];
      const size_t base = ((size_t)n * CD + c) * WD + w0 + wn + l31;
#pragma unroll
      for (int j = 0; j < 2; j++)
        out[base + j * 32] = acc[i][j][reg] + bias + x[base + j * 32];
    }
}

// ---------------------------------------------------------------------------
// ctx: partial[n][h][chunk][64][64] = sum_{w in chunk} exp(K[k,w]) * V[v,w]
// ---------------------------------------------------------------------------
__global__ void __launch_bounds__(256) ctx_kernel(const __bf16* __restrict__ kv,
                                                  float* __restrict__ partial,
                                                  float* __restrict__ ssum) {
  const int chunk = blockIdx.x, h = blockIdx.y, n = blockIdx.z;
  const int t = threadIdx.x, lane = t & 63, wave = t >> 6;
  const int l15 = lane & 15, quad = lane >> 4;
  const int krow = h * 64 + wave * 16 + l15;  // key channel (A row)
  const __bf16* Kp = kv + ((size_t)n * 1024 + krow) * WD + chunk * 1024 + quad * 8;
  const __bf16* Vp = kv + ((size_t)n * 1024 + 512 + h * 64 + l15) * WD + chunk * 1024 + quad * 8;
  f32x4 acc[4];
#pragma unroll
  for (int j = 0; j < 4; j++) acc[j] = (f32x4){0.f, 0.f, 0.f, 0.f};
  float esum = 0.f;
  for (int s = 0; s < 32; s++) {
    bf16x8 kraw = *(const bf16x8*)(Kp + s * 32);
    bf16x8 af;
#pragma unroll
    for (int e = 0; e < 8; e++) {
      const float ev = __expf((float)kraw[e]);
      esum += ev;
      af[e] = (__bf16)ev;
    }
#pragma unroll
    for (int j = 0; j < 4; j++) {
      bf16x8 bv = *(const bf16x8*)(Vp + (size_t)(j * 16) * WD + s * 32);
      acc[j] = __builtin_amdgcn_mfma_f32_16x16x32_bf16(af, bv, acc[j], 0, 0, 0);
    }
  }
  esum += __shfl_xor(esum, 16);
  esum += __shfl_xor(esum, 32);
  float* pp = partial + (((size_t)(n * 8 + h) * 8 + chunk) << 12);
#pragma unroll
  for (int j = 0; j < 4; j++)
#pragma unroll
    for (int r = 0; r < 4; r++) {
      const int kr = wave * 16 + quad * 4 + r;
      const int vc = j * 16 + l15;
      pp[kr * 64 + vc] = acc[j][r];
    }
  if (lane < 16)
    ssum[(((size_t)(n * 8 + h) * 8 + chunk) << 6) + wave * 16 + l15] = esum;
}

// ctx_reduce: sum 8 chunk partials, normalize row k by its exp-sum.
__global__ void __launch_bounds__(256) ctx_reduce_kernel(const float* __restrict__ partial,
                                                         const float* __restrict__ ssum,
                                                         __bf16* __restrict__ ctxB) {
  const int gid = blockIdx.x * 256 + threadIdx.x;  // < 262144 ; [n][h][k][v]
  const int nh = gid >> 12;
  const int kvi = gid & 4095;
  const int k = kvi >> 6;
  float s = 0.f;
#pragma unroll
  for (int c = 0; c < 8; c++) s += ssum[(((size_t)nh * 8 + c) << 6) + k];
  const float* pp = partial + ((size_t)nh << 15) + kvi;
  float v = 0.f;
#pragma unroll
  for (int c = 0; c < 8; c++) v += pp[(size_t)c << 12];
  ctxB[gid] = (__bf16)(v / s);
}

// ---------------------------------------------------------------------------
// mfuse: Mf[n][c][h*64+k] = sum_v Wr[c][h*64+v] * ctx[n][h][k][v]
// ---------------------------------------------------------------------------
__global__ void __launch_bounds__(256) mfuse_kernel(const __bf16* __restrict__ WrB,
                                                    const __bf16* __restrict__ ctxB,
                                                    __bf16* __restrict__ Mf) {
  const int ms = blockIdx.x, h = blockIdx.y, n = blockIdx.z;
  const int t = threadIdx.x, lane = t & 63, wave = t >> 6;
  const int l15 = lane & 15, quad = lane >> 4;
  f32x4 acc[2][4];
#pragma unroll
  for (int i = 0; i < 2; i++)
#pragma unroll
    for (int j = 0; j < 4; j++) acc[i][j] = (f32x4){0.f, 0.f, 0.f, 0.f};
  const __bf16* Ap = WrB + (size_t)(ms * 128 + wave * 32 + l15) * 512 + h * 64 + quad * 8;
  const __bf16* Bp = ctxB + ((size_t)(n * 8 + h) << 12) + (size_t)l15 * 64 + quad * 8;
#pragma unroll
  for (int k0 = 0; k0 < 64; k0 += 32) {
    bf16x8 av[2];
#pragma unroll
    for (int i = 0; i < 2; i++) av[i] = *(const bf16x8*)(Ap + i * 16 * 512 + k0);
#pragma unroll
    for (int j = 0; j < 4; j++) {
      bf16x8 bv = *(const bf16x8*)(Bp + j * 16 * 64 + k0);
#pragma unroll
      for (int i = 0; i < 2; i++)
        acc[i][j] = __builtin_amdgcn_mfma_f32_16x16x32_bf16(av[i], bv, acc[i][j], 0, 0, 0);
    }
  }
#pragma unroll
  for (int i = 0; i < 2; i++)
#pragma unroll
    for (int j = 0; j < 4; j++)
#pragma unroll
      for (int r = 0; r < 4; r++) {
        const int c = ms * 128 + wave * 32 + i * 16 + quad * 4 + r;
        const int col = h * 64 + j * 16 + l15;
        Mf[((size_t)n * 512 + c) * 512 + col] = (__bf16)acc[i][j][r];
      }
}

// ---------------------------------------------------------------------------
extern "C" void kernel_launch(void* const* d_in, const int* in_sizes, int n_in,
                              void* d_out, int out_size, void* d_ws, size_t ws_size,
                              hipStream_t stream) {
  (void)in_sizes; (void)n_in; (void)out_size; (void)ws_size;
  const float* x  = (const float*)d_in[0];
  const float* Wk = (const float*)d_in[1];
  const float* bk = (const float*)d_in[2];
  const float* Wq = (const float*)d_in[3];
  const float* bq = (const float*)d_in[4];
  const float* Wv = (const float*)d_in[5];
  const float* bv = (const float*)d_in[6];
  const float* Wr = (const float*)d_in[7];
  const float* br = (const float*)d_in[8];
  float* out = (float*)d_out;

  char* ws = (char*)d_ws;
  __bf16* xT      = (__bf16*)ws;
  float*  partial = (float*)ws;
  __bf16* ctxB    = (__bf16*)(ws + (16ull << 20));
  __bf16* Mf      = (__bf16*)(ws + (20ull << 20));
  __bf16* kv      = (__bf16*)(ws + (64ull << 20));
  __bf16* qT      = (__bf16*)(ws + (192ull << 20));

  char* scr = (char*)d_out + (124ull << 20);
  __bf16* WkvB = (__bf16*)scr;                         // 1 MiB
  __bf16* WqB  = (__bf16*)(scr + (1ull << 20));        // 0.5 MiB
  __bf16* WrB  = (__bf16*)(scr + (1536ull << 10));     // 0.5 MiB
  float*  bkv  = (float*)(scr + (2ull << 20));         // 4 KiB
  float*  ssum = (float*)(scr + (2ull << 20) + 65536); // 128 KiB

  prep_x_kernel<<<dim3(128, 8, 8), 256, 0, stream>>>(x, xT);
  prep_w_kernel<<<dim3(1024), 256, 0, stream>>>(Wk, Wq, Wv, Wr, bk, bv, WkvB, WqB, WrB, bkv);
  hipFuncSetAttribute((const void*)gemm_kv_kernel,
                      hipFuncAttributeMaxDynamicSharedMemorySize, 131072);
  gemm_kv_kernel<<<dim3(1024), dim3(512), 131072, stream>>>(WkvB, xT, bkv, kv);
  gemm_qT_kernel<<<dim3(64, 4, 8), 256, 0, stream>>>(xT, WqB, bq, qT);
  ctx_kernel<<<dim3(8, 8, 8), 256, 0, stream>>>(kv, partial, ssum);
  ctx_reduce_kernel<<<dim3(1024), 256, 0, stream>>>(partial, ssum, ctxB);
  mfuse_kernel<<<dim3(4, 8, 8), 256, 0, stream>>>(WrB, ctxB, Mf);
  gemm_out_kernel<<<dim3(64, 4, 8), 256, 0, stream>>>(Mf, qT, br, x, out);
}

// Round 2
// 508.862 us; speedup vs baseline: 1.0126x; 1.0126x over previous
//
#include <hip/hip_runtime.h>
#include <hip/hip_bf16.h>
#include <cstdint>

// Fixed problem shape (EfficientAttention): n=8, C=512, W=8192, H=8, hk=hv=64
#define NB 8
#define CD 512
#define WD 8192
#define NH 8

typedef __bf16 bf16x8 __attribute__((ext_vector_type(8)));
typedef float  f32x4  __attribute__((ext_vector_type(4)));
typedef float  f32x16 __attribute__((ext_vector_type(16)));

// async global->LDS, 16B per lane (wave-uniform base + lane*16 dest).
__device__ __forceinline__ void gload_lds16(const __bf16* g, __bf16* l) {
  __builtin_amdgcn_global_load_lds((const __attribute__((address_space(1))) void*)g,
                                   (__attribute__((address_space(3))) void*)l,
                                   16, 0, 0);
}

// ---------------------------------------------------------------------------
// prep_x: x[n][512][8192] fp32  ->  xT[n][8192][512] bf16 (LDS tile transpose)
// ---------------------------------------------------------------------------
__global__ void __launch_bounds__(256) prep_x_kernel(const float* __restrict__ x,
                                                     __bf16* __restrict__ xT) {
  __shared__ float tile[64][65];
  const int n = blockIdx.z, cb = blockIdx.y * 64, wb = blockIdx.x * 64;
  const int t = threadIdx.x;
  const int t63 = t & 63, tg = t >> 6;
  const float* xp = x + ((size_t)n * CD + cb) * WD + wb;
#pragma unroll
  for (int i = 0; i < 16; i++) {
    const int cc = tg * 16 + i;
    tile[cc][t63] = xp[(size_t)cc * WD + t63];
  }
  __syncthreads();
  __bf16* op = xT + ((size_t)n * WD + wb) * CD + cb;
#pragma unroll
  for (int i = 0; i < 16; i++) {
    const int ww = tg * 16 + i;
    op[(size_t)ww * CD + t63] = (__bf16)tile[t63][ww];
  }
}

// ---------------------------------------------------------------------------
// prep_w: convert weights to bf16; pack bk|bv into bkv
// ---------------------------------------------------------------------------
__global__ void __launch_bounds__(256) prep_w_kernel(const float* __restrict__ Wk,
                                                     const float* __restrict__ Wq,
                                                     const float* __restrict__ Wv,
                                                     const float* __restrict__ Wr,
                                                     const float* __restrict__ bk,
                                                     const float* __restrict__ bv,
                                                     __bf16* __restrict__ WkvB,
                                                     __bf16* __restrict__ WqB,
                                                     __bf16* __restrict__ WrB,
                                                     float* __restrict__ bkv) {
  const int gid = blockIdx.x * 256 + threadIdx.x;  // 0..262143
  WkvB[gid]          = (__bf16)Wk[gid];
  WkvB[262144 + gid] = (__bf16)Wv[gid];
  WqB[gid]           = (__bf16)Wq[gid];
  WrB[gid]           = (__bf16)Wr[gid];
  if (gid < 512)       bkv[gid] = bk[gid];
  else if (gid < 1024) bkv[gid] = bv[gid - 512];
}

// ---------------------------------------------------------------------------
// Shared LDS staging for the old 128^2 cores: 2048 16B chunks (A:[0,1024)
// B:[1024,2048)). Chunk (row r, kgroup g) of BK=64 slab -> slot r*8+(g^(r&7)).
// ---------------------------------------------------------------------------
#define STAGE_SLAB(Ak, Bk, lds, t)                                          \
  _Pragma("unroll") for (int rnd = 0; rnd < 8; rnd++) {                     \
    const int c = rnd * 256 + (t);                                          \
    const int cc = c & 1023;                                                \
    const int r = cc >> 3;                                                  \
    const int g = (cc & 7) ^ (r & 7);                                       \
    const __bf16* src = ((c >> 10) ? (Bk) : (Ak)) + (size_t)r * 512 + g * 8;\
    gload_lds16(src, (lds) + (size_t)c * 8);                                \
  }

// 16x16x32 core (verified). A[m][k], BT[n][k], K=512, ld=512.
__device__ __forceinline__ void gemm_lds_core(const __bf16* __restrict__ A,
                                              const __bf16* __restrict__ B,
                                              f32x4 (&acc)[4][4], __bf16* lds) {
  const int t = threadIdx.x;
  const int lane = t & 63, wave = t >> 6;
  const int l15 = lane & 15, quad = lane >> 4;
  const int wm = (wave >> 1) << 6, wn = (wave & 1) << 6;
#pragma unroll 1
  for (int kc = 0; kc < 8; kc++) {
    const __bf16* Ak = A + kc * 64;
    const __bf16* Bk = B + kc * 64;
    STAGE_SLAB(Ak, Bk, lds, t)
    __syncthreads();
#pragma unroll
    for (int k0 = 0; k0 < 2; k0++) {
      const int gk = k0 * 4 + quad;
      bf16x8 av[4], bv[4];
#pragma unroll
      for (int i = 0; i < 4; i++) {
        const int r = wm + i * 16 + l15;
        av[i] = *(const bf16x8*)(lds + (size_t)((r << 3) + (gk ^ (r & 7))) * 8);
      }
#pragma unroll
      for (int j = 0; j < 4; j++) {
        const int r = wn + j * 16 + l15;
        bv[j] = *(const bf16x8*)(lds + (size_t)(8192 + (r << 3) + (gk ^ (r & 7))) * 8);
      }
#pragma unroll
      for (int i = 0; i < 4; i++)
#pragma unroll
        for (int j = 0; j < 4; j++)
          acc[i][j] = __builtin_amdgcn_mfma_f32_16x16x32_bf16(av[i], bv[j], acc[i][j], 0, 0, 0);
    }
    __syncthreads();
  }
}

// 32x32x16 core: same staging/swizzle, half the MFMA instruction count.
__device__ __forceinline__ void gemm_lds_core32(const __bf16* __restrict__ A,
                                                const __bf16* __restrict__ B,
                                                f32x16 (&acc)[2][2], __bf16* lds) {
  const int t = threadIdx.x;
  const int lane = t & 63, wave = t >> 6;
  const int l31 = lane & 31, khalf = lane >> 5;
  const int wm = (wave >> 1) << 6, wn = (wave & 1) << 6;
#pragma unroll 1
  for (int kc = 0; kc < 8; kc++) {
    const __bf16* Ak = A + kc * 64;
    const __bf16* Bk = B + kc * 64;
    STAGE_SLAB(Ak, Bk, lds, t)
    __syncthreads();
#pragma unroll
    for (int kk = 0; kk < 4; kk++) {
      const int g = kk * 2 + khalf;
      bf16x8 av[2], bv[2];
#pragma unroll
      for (int i = 0; i < 2; i++) {
        const int r = wm + i * 32 + l31;
        av[i] = *(const bf16x8*)(lds + (size_t)((r << 3) + (g ^ (r & 7))) * 8);
      }
#pragma unroll
      for (int j = 0; j < 2; j++) {
        const int r = wn + j * 32 + l31;
        bv[j] = *(const bf16x8*)(lds + (size_t)(8192 + (r << 3) + (g ^ (r & 7))) * 8);
      }
#pragma unroll
      for (int i = 0; i < 2; i++)
#pragma unroll
        for (int j = 0; j < 2; j++)
          acc[i][j] = __builtin_amdgcn_mfma_f32_32x32x16_bf16(av[i], bv[j], acc[i][j], 0, 0, 0);
    }
    __syncthreads();
  }
}

// ---------------------------------------------------------------------------
// gemm_kv: 8-phase 256x256 tile, BK=64, 8 waves, 128 KiB LDS dbuf, counted
// vmcnt (T3+T4), setprio (T5), chunk-XOR swizzle (T2), XCD swizzle (T1).
// Round-2 change: cross-phase OPERAND REUSE. Quadrant order per buffer window
// is (0,1)(0,0)(1,0)(1,1); only the changed operand is reloaded from LDS:
//   pos0: av(MH0)+bv(NH1) = 12 reads; pos1: bv(NH0) = 4; pos2: av(MH1) = 8;
//   pos3: bv(NH1) = 4  -> 28 ds_read_b128 per window (was 48).
// Stage schedule (positional) and vmcnt checkpoints are UNCHANGED from the
// round-1 verified skeleton. Per-position fresh-read vs stage-dest
// disjointness re-verified for this quadrant order:
//   pos0 reads Au0,Bv1  stages other-buf Au1   | pos4 reads Au0,Bv1 st other
//   pos1 reads Bv0      stages other-buf Bv1   | pos5 reads Bv0     st other
//   pos2 reads Au1      stages same-buf  Au0 ok| pos6 reads Au1     st Au0 ok
//   pos3 reads Bv1      stages same-buf  Bv0 ok| pos7 reads Bv1     st Bv0 ok
// ---------------------------------------------------------------------------
__device__ __forceinline__ void stage_chunk(const __bf16* __restrict__ g, __bf16* l, int row0) {
  const int lane = threadIdx.x & 63;
  const int r = row0 + (lane >> 3);
  const int sg = lane & 7;
  const int gk = sg ^ (r & 7);  // pre-swizzled global source, linear LDS dest
  gload_lds16(g + (size_t)r * 512 + gk * 8, l + (((r << 3) + sg) << 3));
}

__device__ __forceinline__ void stage_a_unit(const __bf16* __restrict__ g, __bf16* l, int u) {
  const int w8 = (threadIdx.x >> 6) << 3;
  stage_chunk(g, l, u * 64 + w8);
  stage_chunk(g, l, 128 + u * 64 + w8);
}

__device__ __forceinline__ void stage_b_unit(const __bf16* __restrict__ g, __bf16* l, int v) {
  const int w = threadIdx.x >> 6;
  const int r0 = ((w & 3) << 3) + ((w >> 2) << 6) + (v << 5);
  stage_chunk(g, l, r0);
  stage_chunk(g, l, 128 + r0);
}

#define CKPT(N) asm volatile("s_waitcnt vmcnt(" #N ")" ::: "memory")

#define LOAD_AV(BSEL, MH)                                                       \
  _Pragma("unroll") for (int ks = 0; ks < 2; ks++) {                            \
    const int gko = (ks * 4 + quad) ^ (l15 & 7);                                \
    _Pragma("unroll") for (int mi = 0; mi < 4; mi++) {                          \
      const int r = wm128 + (MH) * 64 + mi * 16 + l15;                          \
      av[mi][ks] = *(const bf16x8*)(lds + (BSEL) * 32768 +                      \
                                    (((r << 3) + gko) << 3));                   \
    }                                                                           \
  }

#define LOAD_BV(BSEL, NH)                                                       \
  _Pragma("unroll") for (int ks = 0; ks < 2; ks++) {                            \
    const int gko = (ks * 4 + quad) ^ (l15 & 7);                                \
    _Pragma("unroll") for (int nj = 0; nj < 2; nj++) {                          \
      const int r = wn64 + (NH) * 32 + nj * 16 + l15;                           \
      bv[nj][ks] = *(const bf16x8*)(lds + (BSEL) * 32768 + 16384 +              \
                                    (((r << 3) + gko) << 3));                   \
    }                                                                           \
  }

#define PHASE_CORE(MH, NH, STAGE_STMT, CKPT_STMT)                               \
  do {                                                                          \
    STAGE_STMT;                                                                 \
    __builtin_amdgcn_s_barrier();                                               \
    asm volatile("s_waitcnt lgkmcnt(0)" ::: "memory");                          \
    __builtin_amdgcn_sched_barrier(0);                                          \
    __builtin_amdgcn_s_setprio(1);                                              \
    _Pragma("unroll") for (int ks = 0; ks < 2; ks++)                            \
      _Pragma("unroll") for (int mi = 0; mi < 4; mi++)                          \
        _Pragma("unroll") for (int nj = 0; nj < 2; nj++)                        \
          acc[(MH) * 4 + mi][(NH) * 2 + nj] =                                   \
              __builtin_amdgcn_mfma_f32_16x16x32_bf16(                          \
                  av[mi][ks], bv[nj][ks], acc[(MH) * 4 + mi][(NH) * 2 + nj],    \
                  0, 0, 0);                                                     \
    __builtin_amdgcn_s_setprio(0);                                              \
    CKPT_STMT;                                                                  \
    __builtin_amdgcn_s_barrier();                                               \
  } while (0)

__global__ void __launch_bounds__(512, 2) gemm_kv_kernel(const __bf16* __restrict__ WkvB,
                                                         const __bf16* __restrict__ xT,
                                                         const float* __restrict__ bkv,
                                                         __bf16* __restrict__ kv) {
  extern __shared__ __bf16 lds[];
  const int t = threadIdx.x;
  const int lane = t & 63;
  const int l15 = lane & 15, quad = lane >> 4;
  const int wave = t >> 6;
  const int wm128 = (wave >> 2) << 7;  // 0 / 128
  const int wn64 = (wave & 3) << 6;    // 0 / 64 / 128 / 192

  // XCD-bijective swizzle over 1024 blocks: each XCD gets a contiguous chunk;
  // m-tile fastest so 4 blocks sharing a 256KB xT panel co-reside per XCD L2.
  const int bid = blockIdx.x;
  const int swz = (bid & 7) * 128 + (bid >> 3);
  const int m0 = (swz & 3) << 8;
  const int w0 = ((swz >> 2) & 31) << 8;
  const int n = swz >> 7;

  const __bf16* Ab = WkvB + (size_t)m0 * 512;
  const __bf16* Bb = xT + ((size_t)n * WD + w0) * 512;

  f32x4 acc[8][4];
#pragma unroll
  for (int i = 0; i < 8; i++)
#pragma unroll
    for (int j = 0; j < 4; j++) acc[i][j] = (f32x4){0.f, 0.f, 0.f, 0.f};

  bf16x8 av[4][2], bv[2][2];

  __bf16* const lA0 = lds;
  __bf16* const lB0 = lds + 16384;
  __bf16* const lA1 = lds + 32768;
  __bf16* const lB1 = lds + 49152;

  // prologue: slab0 fully + slab1 A0,B0 (12 loads/thread), drain to 4.
  stage_a_unit(Ab, lA0, 0);
  stage_b_unit(Bb, lB0, 0);
  stage_a_unit(Ab, lA0, 1);
  stage_b_unit(Bb, lB0, 1);
  stage_a_unit(Ab + 64, lA1, 0);
  stage_b_unit(Bb + 64, lB1, 0);
  asm volatile("s_waitcnt vmcnt(4)" ::: "memory");
  __builtin_amdgcn_s_barrier();

#pragma unroll 1
  for (int i = 0; i < 3; i++) {
    const __bf16* As1 = Ab + (2 * i + 1) * 64;
    const __bf16* Bs1 = Bb + (2 * i + 1) * 64;
    const __bf16* As2 = Ab + (2 * i + 2) * 64;
    const __bf16* Bs2 = Bb + (2 * i + 2) * 64;
    const __bf16* As3 = Ab + (2 * i + 3) * 64;
    const __bf16* Bs3 = Bb + (2 * i + 3) * 64;
    // buf0 window (slab 2i), quadrant order (0,1)(0,0)(1,0)(1,1)
    LOAD_AV(0, 0); LOAD_BV(0, 1);
    PHASE_CORE(0, 1, stage_a_unit(As1, lA1, 1), (void)0);
    LOAD_BV(0, 0);
    PHASE_CORE(0, 0, stage_b_unit(Bs1, lB1, 1), (void)0);
    LOAD_AV(0, 1);
    PHASE_CORE(1, 0, stage_a_unit(As2, lA0, 0), (void)0);
    LOAD_BV(0, 1);
    PHASE_CORE(1, 1, stage_b_unit(Bs2, lB0, 0), CKPT(4));
    // buf1 window (slab 2i+1), same order
    LOAD_AV(1, 0); LOAD_BV(1, 1);
    PHASE_CORE(0, 1, stage_a_unit(As2, lA0, 1), (void)0);
    LOAD_BV(1, 0);
    PHASE_CORE(0, 0, stage_b_unit(Bs2, lB0, 1), (void)0);
    LOAD_AV(1, 1);
    PHASE_CORE(1, 0, stage_a_unit(As3, lA1, 0), (void)0);
    LOAD_BV(1, 1);
    PHASE_CORE(1, 1, stage_b_unit(Bs3, lB1, 0), CKPT(4));
  }
  // tail (slabs 6,7): only slab7's A1,B1 remain to stage; drain once.
  LOAD_AV(0, 0); LOAD_BV(0, 1);
  PHASE_CORE(0, 1, stage_a_unit(Ab + 7 * 64, lA1, 1), (void)0);
  LOAD_BV(0, 0);
  PHASE_CORE(0, 0, stage_b_unit(Bb + 7 * 64, lB1, 1), (void)0);
  LOAD_AV(0, 1);
  PHASE_CORE(1, 0, (void)0, (void)0);
  LOAD_BV(0, 1);
  PHASE_CORE(1, 1, (void)0, CKPT(0));
  LOAD_AV(1, 0); LOAD_BV(1, 1);
  PHASE_CORE(0, 1, (void)0, (void)0);
  LOAD_BV(1, 0);
  PHASE_CORE(0, 0, (void)0, (void)0);
  LOAD_AV(1, 1);
  PHASE_CORE(1, 0, (void)0, (void)0);
  LOAD_BV(1, 1);
  PHASE_CORE(1, 1, (void)0, (void)0);

  // epilogue: D col=lane&15 (w), row=quad*4+reg (m); bias over m.
#pragma unroll
  for (int MI = 0; MI < 8; MI++)
#pragma unroll
    for (int r = 0; r < 4; r++) {
      const int m = m0 + wm128 + MI * 16 + quad * 4 + r;
      const float bias = bkv[m];
      __bf16* rp = kv + ((size_t)n * 1024 + m) * WD + w0 + wn64 + l15;
#pragma unroll
      for (int j = 0; j < 4; j++) rp[j * 16] = (__bf16)(acc[MI][j][r] + bias);
    }
}

// gemm_qT + fused Q-softmax epilogue.
// qT[n][8192][512] bf16 : queries transposed (w-major), softmaxed per head.
__global__ void __launch_bounds__(256) gemm_qT_kernel(const __bf16* __restrict__ xT,
                                                      const __bf16* __restrict__ WqB,
                                                      const float* __restrict__ bq,
                                                      __bf16* __restrict__ qT) {
  __shared__ __bf16 lds[16384];
  const int n = blockIdx.z, w0 = blockIdx.x * 128, q0 = blockIdx.y * 128;
  f32x4 acc[4][4];
#pragma unroll
  for (int i = 0; i < 4; i++)
#pragma unroll
    for (int j = 0; j < 4; j++) acc[i][j] = (f32x4){0.f, 0.f, 0.f, 0.f};
  gemm_lds_core(xT + ((size_t)n * WD + w0) * 512, WqB + (size_t)q0 * 512, acc, lds);
  const int t = threadIdx.x, lane = t & 63, wave = t >> 6;
  const int l15 = lane & 15, quad = lane >> 4;
  const int wm = (wave >> 1) << 6, wn = (wave & 1) << 6;
  float bqv[4];
#pragma unroll
  for (int j = 0; j < 4; j++) bqv[j] = bq[q0 + wn + j * 16 + l15];
#pragma unroll
  for (int i = 0; i < 4; i++)
#pragma unroll
    for (int r = 0; r < 4; r++) {
      float e[4];
      float s = 0.f;
#pragma unroll
      for (int j = 0; j < 4; j++) {
        e[j] = __expf(acc[i][j][r] + bqv[j]);
        s += e[j];
      }
      s += __shfl_xor(s, 1);
      s += __shfl_xor(s, 2);
      s += __shfl_xor(s, 4);
      s += __shfl_xor(s, 8);
      const float inv = 1.0f / s;
      const int w = w0 + wm + i * 16 + quad * 4 + r;
      __bf16* rp = qT + ((size_t)n * WD + w) * 512 + q0 + wn + l15;
#pragma unroll
      for (int j = 0; j < 4; j++) rp[j * 16] = (__bf16)(e[j] * inv);
    }
}

// final: out[n][512][8192] fp32 = Mf[n] (512x512) @ Qsm + br + x
__global__ void __launch_bounds__(256) gemm_out_kernel(const __bf16* __restrict__ Mf,
                                                       const __bf16* __restrict__ qT,
                                                       const float* __restrict__ br,
                                                       const float* __restrict__ x,
                                                       float* __restrict__ out) {
  __shared__ __bf16 lds[16384];
  const int n = blockIdx.z, c0 = blockIdx.y * 128, w0 = blockIdx.x * 128;
  f32x16 acc[2][2];
#pragma unroll
  for (int i = 0; i < 2; i++)
#pragma unroll
    for (int j = 0; j < 2; j++)
#pragma unroll
      for (int r = 0; r < 16; r++) acc[i][j][r] = 0.f;
  gemm_lds_core32(Mf + ((size_t)n * 512 + c0) * 512, qT + ((size_t)n * WD + w0) * 512, acc, lds);
  const int t = threadIdx.x, lane = t & 63, wave = t >> 6;
  const int l31 = lane & 31, khalf = lane >> 5;
  const int wm = (wave >> 1) << 6, wn = (wave & 1) << 6;
#pragma unroll
  for (int i = 0; i < 2; i++)
#pragma unroll
    for (int reg = 0; reg < 16; reg++) {
      const int row = (reg & 3) + 8 * (reg >> 2) + 4 * khalf;
      const int c = c0 + wm + i * 32 + row;
      const float bias = br[c];
      const size_t base = ((size_t)n * CD + c) * WD + w0 + wn + l31;
#pragma unroll
      for (int j = 0; j < 2; j++)
        out[base + j * 32] = acc[i][j][reg] + bias + x[base + j * 32];
    }
}

// ---------------------------------------------------------------------------
// ctx: partial[n][h][chunk][64][64] = sum_{w in chunk} exp(K[k,w]) * V[v,w]
// ---------------------------------------------------------------------------
__global__ void __launch_bounds__(256) ctx_kernel(const __bf16* __restrict__ kv,
                                                  float* __restrict__ partial,
                                                  float* __restrict__ ssum) {
  const int chunk = blockIdx.x, h = blockIdx.y, n = blockIdx.z;
  const int t = threadIdx.x, lane = t & 63, wave = t >> 6;
  const int l15 = lane & 15, quad = lane >> 4;
  const int krow = h * 64 + wave * 16 + l15;  // key channel (A row)
  const __bf16* Kp = kv + ((size_t)n * 1024 + krow) * WD + chunk * 1024 + quad * 8;
  const __bf16* Vp = kv + ((size_t)n * 1024 + 512 + h * 64 + l15) * WD + chunk * 1024 + quad * 8;
  f32x4 acc[4];
#pragma unroll
  for (int j = 0; j < 4; j++) acc[j] = (f32x4){0.f, 0.f, 0.f, 0.f};
  float esum = 0.f;
  for (int s = 0; s < 32; s++) {
    bf16x8 kraw = *(const bf16x8*)(Kp + s * 32);
    bf16x8 af;
#pragma unroll
    for (int e = 0; e < 8; e++) {
      const float ev = __expf((float)kraw[e]);
      esum += ev;
      af[e] = (__bf16)ev;
    }
#pragma unroll
    for (int j = 0; j < 4; j++) {
      bf16x8 bv = *(const bf16x8*)(Vp + (size_t)(j * 16) * WD + s * 32);
      acc[j] = __builtin_amdgcn_mfma_f32_16x16x32_bf16(af, bv, acc[j], 0, 0, 0);
    }
  }
  esum += __shfl_xor(esum, 16);
  esum += __shfl_xor(esum, 32);
  float* pp = partial + (((size_t)(n * 8 + h) * 8 + chunk) << 12);
#pragma unroll
  for (int j = 0; j < 4; j++)
#pragma unroll
    for (int r = 0; r < 4; r++) {
      const int kr = wave * 16 + quad * 4 + r;
      const int vc = j * 16 + l15;
      pp[kr * 64 + vc] = acc[j][r];
    }
  if (lane < 16)
    ssum[(((size_t)(n * 8 + h) * 8 + chunk) << 6) + wave * 16 + l15] = esum;
}

// ctx_reduce: sum 8 chunk partials, normalize row k by its exp-sum.
__global__ void __launch_bounds__(256) ctx_reduce_kernel(const float* __restrict__ partial,
                                                         const float* __restrict__ ssum,
                                                         __bf16* __restrict__ ctxB) {
  const int gid = blockIdx.x * 256 + threadIdx.x;  // < 262144 ; [n][h][k][v]
  const int nh = gid >> 12;
  const int kvi = gid & 4095;
  const int k = kvi >> 6;
  float s = 0.f;
#pragma unroll
  for (int c = 0; c < 8; c++) s += ssum[(((size_t)nh * 8 + c) << 6) + k];
  const float* pp = partial + ((size_t)nh << 15) + kvi;
  float v = 0.f;
#pragma unroll
  for (int c = 0; c < 8; c++) v += pp[(size_t)c << 12];
  ctxB[gid] = (__bf16)(v / s);
}

// ---------------------------------------------------------------------------
// mfuse: Mf[n][c][h*64+k] = sum_v Wr[c][h*64+v] * ctx[n][h][k][v]
// ---------------------------------------------------------------------------
__global__ void __launch_bounds__(256) mfuse_kernel(const __bf16* __restrict__ WrB,
                                                    const __bf16* __restrict__ ctxB,
                                                    __bf16* __restrict__ Mf) {
  const int ms = blockIdx.x, h = blockIdx.y, n = blockIdx.z;
  const int t = threadIdx.x, lane = t & 63, wave = t >> 6;
  const int l15 = lane & 15, quad = lane >> 4;
  f32x4 acc[2][4];
#pragma unroll
  for (int i = 0; i < 2; i++)
#pragma unroll
    for (int j = 0; j < 4; j++) acc[i][j] = (f32x4){0.f, 0.f, 0.f, 0.f};
  const __bf16* Ap = WrB + (size_t)(ms * 128 + wave * 32 + l15) * 512 + h * 64 + quad * 8;
  const __bf16* Bp = ctxB + ((size_t)(n * 8 + h) << 12) + (size_t)l15 * 64 + quad * 8;
#pragma unroll
  for (int k0 = 0; k0 < 64; k0 += 32) {
    bf16x8 av[2];
#pragma unroll
    for (int i = 0; i < 2; i++) av[i] = *(const bf16x8*)(Ap + i * 16 * 512 + k0);
#pragma unroll
    for (int j = 0; j < 4; j++) {
      bf16x8 bv = *(const bf16x8*)(Bp + j * 16 * 64 + k0);
#pragma unroll
      for (int i = 0; i < 2; i++)
        acc[i][j] = __builtin_amdgcn_mfma_f32_16x16x32_bf16(av[i], bv, acc[i][j], 0, 0, 0);
    }
  }
#pragma unroll
  for (int i = 0; i < 2; i++)
#pragma unroll
    for (int j = 0; j < 4; j++)
#pragma unroll
      for (int r = 0; r < 4; r++) {
        const int c = ms * 128 + wave * 32 + i * 16 + quad * 4 + r;
        const int col = h * 64 + j * 16 + l15;
        Mf[((size_t)n * 512 + c) * 512 + col] = (__bf16)acc[i][j][r];
      }
}

// ---------------------------------------------------------------------------
extern "C" void kernel_launch(void* const* d_in, const int* in_sizes, int n_in,
                              void* d_out, int out_size, void* d_ws, size_t ws_size,
                              hipStream_t stream) {
  (void)in_sizes; (void)n_in; (void)out_size; (void)ws_size;
  const float* x  = (const float*)d_in[0];
  const float* Wk = (const float*)d_in[1];
  const float* bk = (const float*)d_in[2];
  const float* Wq = (const float*)d_in[3];
  const float* bq = (const float*)d_in[4];
  const float* Wv = (const float*)d_in[5];
  const float* bv = (const float*)d_in[6];
  const float* Wr = (const float*)d_in[7];
  const float* br = (const float*)d_in[8];
  float* out = (float*)d_out;

  char* ws = (char*)d_ws;
  __bf16* xT      = (__bf16*)ws;
  float*  partial = (float*)ws;
  __bf16* ctxB    = (__bf16*)(ws + (16ull << 20));
  __bf16* Mf      = (__bf16*)(ws + (20ull << 20));
  __bf16* kv      = (__bf16*)(ws + (64ull << 20));
  __bf16* qT      = (__bf16*)(ws + (192ull << 20));

  char* scr = (char*)d_out + (124ull << 20);
  __bf16* WkvB = (__bf16*)scr;                         // 1 MiB
  __bf16* WqB  = (__bf16*)(scr + (1ull << 20));        // 0.5 MiB
  __bf16* WrB  = (__bf16*)(scr + (1536ull << 10));     // 0.5 MiB
  float*  bkv  = (float*)(scr + (2ull << 20));         // 4 KiB
  float*  ssum = (float*)(scr + (2ull << 20) + 65536); // 128 KiB

  prep_x_kernel<<<dim3(128, 8, 8), 256, 0, stream>>>(x, xT);
  prep_w_kernel<<<dim3(1024), 256, 0, stream>>>(Wk, Wq, Wv, Wr, bk, bv, WkvB, WqB, WrB, bkv);
  hipFuncSetAttribute((const void*)gemm_kv_kernel,
                      hipFuncAttributeMaxDynamicSharedMemorySize, 131072);
  gemm_kv_kernel<<<dim3(1024), dim3(512), 131072, stream>>>(WkvB, xT, bkv, kv);
  gemm_qT_kernel<<<dim3(64, 4, 8), 256, 0, stream>>>(xT, WqB, bq, qT);
  ctx_kernel<<<dim3(8, 8, 8), 256, 0, stream>>>(kv, partial, ssum);
  ctx_reduce_kernel<<<dim3(1024), 256, 0, stream>>>(partial, ssum, ctxB);
  mfuse_kernel<<<dim3(4, 8, 8), 256, 0, stream>>>(WrB, ctxB, Mf);
  gemm_out_kernel<<<dim3(64, 4, 8), 256, 0, stream>>>(Mf, qT, br, x, out);
}

// Round 3
// 504.578 us; speedup vs baseline: 1.0212x; 1.0085x over previous
//
#include <hip/hip_runtime.h>
#include <hip/hip_bf16.h>
#include <cstdint>

// Fixed problem shape (EfficientAttention): n=8, C=512, W=8192, H=8, hk=hv=64
#define NB 8
#define CD 512
#define WD 8192
#define NH 8

typedef __bf16 bf16x2 __attribute__((ext_vector_type(2)));
typedef __bf16 bf16x8 __attribute__((ext_vector_type(8)));
typedef float  f32x4  __attribute__((ext_vector_type(4)));
typedef float  f32x16 __attribute__((ext_vector_type(16)));

// async global->LDS, 16B per lane (wave-uniform base + lane*16 dest).
__device__ __forceinline__ void gload_lds16(const __bf16* g, __bf16* l) {
  __builtin_amdgcn_global_load_lds((const __attribute__((address_space(1))) void*)g,
                                   (__attribute__((address_space(3))) void*)l,
                                   16, 0, 0);
}

// ---------------------------------------------------------------------------
// prep_x: x[n][512][8192] fp32 -> xT[n][8192][512] bf16.
// 128(c) x 64(w) tile; reads 256B rows, writes 256B rows via bf16x2.
// ---------------------------------------------------------------------------
__global__ void __launch_bounds__(256) prep_x_kernel(const float* __restrict__ x,
                                                     __bf16* __restrict__ xT) {
  __shared__ float tile[128][65];
  const int n = blockIdx.z, cb = blockIdx.y * 128, wb = blockIdx.x * 64;
  const int t = threadIdx.x;
  const int t63 = t & 63, tg = t >> 6;
  const float* xp = x + ((size_t)n * CD + cb) * WD + wb;
#pragma unroll
  for (int i = 0; i < 32; i++) {
    const int cc = tg * 32 + i;
    tile[cc][t63] = xp[(size_t)cc * WD + t63];
  }
  __syncthreads();
  __bf16* op = xT + ((size_t)n * WD + wb) * CD + cb;
#pragma unroll
  for (int i = 0; i < 16; i++) {
    const int ww = tg * 16 + i;
    const float a = tile[t63 * 2][ww];
    const float b = tile[t63 * 2 + 1][ww];
    *(bf16x2*)(op + (size_t)ww * CD + t63 * 2) = (bf16x2){(__bf16)a, (__bf16)b};
  }
}

// ---------------------------------------------------------------------------
// prep_w: convert weights to bf16; pack bk|bv into bkv
// ---------------------------------------------------------------------------
__global__ void __launch_bounds__(256) prep_w_kernel(const float* __restrict__ Wk,
                                                     const float* __restrict__ Wq,
                                                     const float* __restrict__ Wv,
                                                     const float* __restrict__ Wr,
                                                     const float* __restrict__ bk,
                                                     const float* __restrict__ bv,
                                                     __bf16* __restrict__ WkvB,
                                                     __bf16* __restrict__ WqB,
                                                     __bf16* __restrict__ WrB,
                                                     float* __restrict__ bkv) {
  const int gid = blockIdx.x * 256 + threadIdx.x;  // 0..262143
  WkvB[gid]          = (__bf16)Wk[gid];
  WkvB[262144 + gid] = (__bf16)Wv[gid];
  WqB[gid]           = (__bf16)Wq[gid];
  WrB[gid]           = (__bf16)Wr[gid];
  if (gid < 512)       bkv[gid] = bk[gid];
  else if (gid < 1024) bkv[gid] = bv[gid - 512];
}

// ---------------------------------------------------------------------------
// Shared LDS staging: 2048 16B chunks (A:[0,1024) B:[1024,2048)).
// Chunk (row r, kgroup g) of current BK=64 slab -> slot r*8 + (g^(r&7)).
// ---------------------------------------------------------------------------
#define STAGE_SLAB(Ak, Bk, lds, t)                                          \
  _Pragma("unroll") for (int rnd = 0; rnd < 8; rnd++) {                     \
    const int c = rnd * 256 + (t);                                          \
    const int cc = c & 1023;                                                \
    const int r = cc >> 3;                                                  \
    const int g = (cc & 7) ^ (r & 7);                                       \
    const __bf16* src = ((c >> 10) ? (Bk) : (Ak)) + (size_t)r * 512 + g * 8;\
    gload_lds16(src, (lds) + (size_t)c * 8);                                \
  }

// 16x16x32 core (verified). A[m][k], BT[n][k], K=512, ld=512.
__device__ __forceinline__ void gemm_lds_core(const __bf16* __restrict__ A,
                                              const __bf16* __restrict__ B,
                                              f32x4 (&acc)[4][4], __bf16* lds) {
  const int t = threadIdx.x;
  const int lane = t & 63, wave = t >> 6;
  const int l15 = lane & 15, quad = lane >> 4;
  const int wm = (wave >> 1) << 6, wn = (wave & 1) << 6;
#pragma unroll 1
  for (int kc = 0; kc < 8; kc++) {
    const __bf16* Ak = A + kc * 64;
    const __bf16* Bk = B + kc * 64;
    STAGE_SLAB(Ak, Bk, lds, t)
    __syncthreads();
#pragma unroll
    for (int k0 = 0; k0 < 2; k0++) {
      const int gk = k0 * 4 + quad;
      bf16x8 av[4], bv[4];
#pragma unroll
      for (int i = 0; i < 4; i++) {
        const int r = wm + i * 16 + l15;
        av[i] = *(const bf16x8*)(lds + (size_t)((r << 3) + (gk ^ (r & 7))) * 8);
      }
#pragma unroll
      for (int j = 0; j < 4; j++) {
        const int r = wn + j * 16 + l15;
        bv[j] = *(const bf16x8*)(lds + (size_t)(8192 + (r << 3) + (gk ^ (r & 7))) * 8);
      }
#pragma unroll
      for (int i = 0; i < 4; i++)
#pragma unroll
        for (int j = 0; j < 4; j++)
          acc[i][j] = __builtin_amdgcn_mfma_f32_16x16x32_bf16(av[i], bv[j], acc[i][j], 0, 0, 0);
    }
    __syncthreads();
  }
}

// 32x32x16 core: same staging/swizzle, half the MFMA instruction count.
// D: col=lane&31, row=(reg&3)+8*(reg>>2)+4*(lane>>5)  (m74/m101 verified).
__device__ __forceinline__ void gemm_lds_core32(const __bf16* __restrict__ A,
                                                const __bf16* __restrict__ B,
                                                f32x16 (&acc)[2][2], __bf16* lds) {
  const int t = threadIdx.x;
  const int lane = t & 63, wave = t >> 6;
  const int l31 = lane & 31, khalf = lane >> 5;
  const int wm = (wave >> 1) << 6, wn = (wave & 1) << 6;
#pragma unroll 1
  for (int kc = 0; kc < 8; kc++) {
    const __bf16* Ak = A + kc * 64;
    const __bf16* Bk = B + kc * 64;
    STAGE_SLAB(Ak, Bk, lds, t)
    __syncthreads();
#pragma unroll
    for (int kk = 0; kk < 4; kk++) {
      const int g = kk * 2 + khalf;
      bf16x8 av[2], bv[2];
#pragma unroll
      for (int i = 0; i < 2; i++) {
        const int r = wm + i * 32 + l31;
        av[i] = *(const bf16x8*)(lds + (size_t)((r << 3) + (g ^ (r & 7))) * 8);
      }
#pragma unroll
      for (int j = 0; j < 2; j++) {
        const int r = wn + j * 32 + l31;
        bv[j] = *(const bf16x8*)(lds + (size_t)(8192 + (r << 3) + (g ^ (r & 7))) * 8);
      }
#pragma unroll
      for (int i = 0; i < 2; i++)
#pragma unroll
        for (int j = 0; j < 2; j++)
          acc[i][j] = __builtin_amdgcn_mfma_f32_32x32x16_bf16(av[i], bv[j], acc[i][j], 0, 0, 0);
    }
    __syncthreads();
  }
}

// ---------------------------------------------------------------------------
// gemm_kvq: merged kv + qT GEMMs in ONE dispatch (independent work; merged so
// the scheduler overlaps their barrier stalls / tails; dispatch order
// interleaves roles since y is the middle grid dim).
//   y <  8 : kv[n][1024][8192] = Wkv @ xT^T + bkv   (32x32 core, m0=y*128)
//   y >= 8 : qT[n][8192][512]  = softmax_head(Wq @ x + bq), w-major
// ---------------------------------------------------------------------------
__global__ void __launch_bounds__(256) gemm_kvq_kernel(const __bf16* __restrict__ WkvB,
                                                       const __bf16* __restrict__ WqB,
                                                       const __bf16* __restrict__ xT,
                                                       const float* __restrict__ bkv,
                                                       const float* __restrict__ bq,
                                                       __bf16* __restrict__ kv,
                                                       __bf16* __restrict__ qT) {
  __shared__ __bf16 lds[16384];
  const int n = blockIdx.z, w0 = blockIdx.x * 128;
  const int t = threadIdx.x, lane = t & 63, wave = t >> 6;

  if (blockIdx.y < 8) {
    // ----- kv path (round-0 gemm_kv) -----
    const int m0 = blockIdx.y * 128;
    f32x16 acc[2][2];
#pragma unroll
    for (int i = 0; i < 2; i++)
#pragma unroll
      for (int j = 0; j < 2; j++)
#pragma unroll
        for (int r = 0; r < 16; r++) acc[i][j][r] = 0.f;
    gemm_lds_core32(WkvB + (size_t)m0 * 512, xT + ((size_t)n * WD + w0) * 512, acc, lds);
    const int l31 = lane & 31, khalf = lane >> 5;
    const int wm = (wave >> 1) << 6, wn = (wave & 1) << 6;
    __bf16* outp = kv + (size_t)n * 1024 * WD + w0 + wn + l31;
#pragma unroll
    for (int i = 0; i < 2; i++)
#pragma unroll
      for (int reg = 0; reg < 16; reg++) {
        const int row = (reg & 3) + 8 * (reg >> 2) + 4 * khalf;
        const int m = m0 + wm + i * 32 + row;
        const float bias = bkv[m];
        __bf16* rp = outp + (size_t)m * WD;
#pragma unroll
        for (int j = 0; j < 2; j++) rp[j * 32] = (__bf16)(acc[i][j][reg] + bias);
      }
  } else {
    // ----- qT path (round-0 gemm_qT + fused Q-softmax) -----
    const int q0 = (blockIdx.y - 8) * 128;
    f32x4 acc[4][4];
#pragma unroll
    for (int i = 0; i < 4; i++)
#pragma unroll
      for (int j = 0; j < 4; j++) acc[i][j] = (f32x4){0.f, 0.f, 0.f, 0.f};
    gemm_lds_core(xT + ((size_t)n * WD + w0) * 512, WqB + (size_t)q0 * 512, acc, lds);
    const int l15 = lane & 15, quad = lane >> 4;
    const int wm = (wave >> 1) << 6, wn = (wave & 1) << 6;
    float bqv[4];
#pragma unroll
    for (int j = 0; j < 4; j++) bqv[j] = bq[q0 + wn + j * 16 + l15];
#pragma unroll
    for (int i = 0; i < 4; i++)
#pragma unroll
      for (int r = 0; r < 4; r++) {
        float e[4];
        float s = 0.f;
#pragma unroll
        for (int j = 0; j < 4; j++) {
          e[j] = __expf(acc[i][j][r] + bqv[j]);
          s += e[j];
        }
        s += __shfl_xor(s, 1);
        s += __shfl_xor(s, 2);
        s += __shfl_xor(s, 4);
        s += __shfl_xor(s, 8);
        const float inv = 1.0f / s;
        const int w = w0 + wm + i * 16 + quad * 4 + r;
        __bf16* rp = qT + ((size_t)n * WD + w) * 512 + q0 + wn + l15;
#pragma unroll
        for (int j = 0; j < 4; j++) rp[j * 16] = (__bf16)(e[j] * inv);
      }
  }
}

// final: out[n][512][8192] fp32 = Mf[n] (512x512) @ Qsm + br + x
__global__ void __launch_bounds__(256) gemm_out_kernel(const __bf16* __restrict__ Mf,
                                                       const __bf16* __restrict__ qT,
                                                       const float* __restrict__ br,
                                                       const float* __restrict__ x,
                                                       float* __restrict__ out) {
  __shared__ __bf16 lds[16384];
  const int n = blockIdx.z, c0 = blockIdx.y * 128, w0 = blockIdx.x * 128;
  f32x16 acc[2][2];
#pragma unroll
  for (int i = 0; i < 2; i++)
#pragma unroll
    for (int j = 0; j < 2; j++)
#pragma unroll
      for (int r = 0; r < 16; r++) acc[i][j][r] = 0.f;
  gemm_lds_core32(Mf + ((size_t)n * 512 + c0) * 512, qT + ((size_t)n * WD + w0) * 512, acc, lds);
  const int t = threadIdx.x, lane = t & 63, wave = t >> 6;
  const int l31 = lane & 31, khalf = lane >> 5;
  const int wm = (wave >> 1) << 6, wn = (wave & 1) << 6;
#pragma unroll
  for (int i = 0; i < 2; i++)
#pragma unroll
    for (int reg = 0; reg < 16; reg++) {
      const int row = (reg & 3) + 8 * (reg >> 2) + 4 * khalf;
      const int c = c0 + wm + i * 32 + row;
      const float bias = br[c];
      const size_t base = ((size_t)n * CD + c) * WD + w0 + wn + l31;
#pragma unroll
      for (int j = 0; j < 2; j++)
        out[base + j * 32] = acc[i][j][reg] + bias + x[base + j * 32];
    }
}

// ---------------------------------------------------------------------------
// ctx: partial[n][h][chunk][64][64] = sum_{w in chunk} exp(K[k,w]) * V[v,w]
// (unnormalized; exp is overflow-safe since |keys| <~ 3). Also emits per-row
// partial exp-sums ssum[n][h][chunk][64] via quad shuffle reduce.
// ---------------------------------------------------------------------------
__global__ void __launch_bounds__(256) ctx_kernel(const __bf16* __restrict__ kv,
                                                  float* __restrict__ partial,
                                                  float* __restrict__ ssum) {
  const int chunk = blockIdx.x, h = blockIdx.y, n = blockIdx.z;
  const int t = threadIdx.x, lane = t & 63, wave = t >> 6;
  const int l15 = lane & 15, quad = lane >> 4;
  const int krow = h * 64 + wave * 16 + l15;  // key channel (A row)
  const __bf16* Kp = kv + ((size_t)n * 1024 + krow) * WD + chunk * 1024 + quad * 8;
  const __bf16* Vp = kv + ((size_t)n * 1024 + 512 + h * 64 + l15) * WD + chunk * 1024 + quad * 8;
  f32x4 acc[4];
#pragma unroll
  for (int j = 0; j < 4; j++) acc[j] = (f32x4){0.f, 0.f, 0.f, 0.f};
  float esum = 0.f;
  for (int s = 0; s < 32; s++) {
    bf16x8 kraw = *(const bf16x8*)(Kp + s * 32);
    bf16x8 af;
#pragma unroll
    for (int e = 0; e < 8; e++) {
      const float ev = __expf((float)kraw[e]);
      esum += ev;
      af[e] = (__bf16)ev;
    }
#pragma unroll
    for (int j = 0; j < 4; j++) {
      bf16x8 bv = *(const bf16x8*)(Vp + (size_t)(j * 16) * WD + s * 32);
      acc[j] = __builtin_amdgcn_mfma_f32_16x16x32_bf16(af, bv, acc[j], 0, 0, 0);
    }
  }
  // reduce esum across the 4 quads sharing l15 (lanes differ in bits 4,5)
  esum += __shfl_xor(esum, 16);
  esum += __shfl_xor(esum, 32);
  float* pp = partial + (((size_t)(n * 8 + h) * 8 + chunk) << 12);
#pragma unroll
  for (int j = 0; j < 4; j++)
#pragma unroll
    for (int r = 0; r < 4; r++) {
      const int kr = wave * 16 + quad * 4 + r;
      const int vc = j * 16 + l15;
      pp[kr * 64 + vc] = acc[j][r];
    }
  if (lane < 16)
    ssum[(((size_t)(n * 8 + h) * 8 + chunk) << 6) + wave * 16 + l15] = esum;
}

// ---------------------------------------------------------------------------
// ctx_finish: merged ctx_reduce + mfuse. One block per (h,n).
// Phase 1: sum 8 chunk partials, normalize -> LDS ctx tile [64][72] bf16.
// Phase 2: Mf[n][c][h*64+k] = sum_v Wr[c][h*64+v] * ctx[k][v], B from LDS.
// ---------------------------------------------------------------------------
__global__ void __launch_bounds__(256) ctx_finish_kernel(const float* __restrict__ partial,
                                                         const float* __restrict__ ssum,
                                                         const __bf16* __restrict__ WrB,
                                                         __bf16* __restrict__ Mf) {
  __shared__ __bf16 ctx_tile[64][72];
  __shared__ float srow[64];
  const int h = blockIdx.x, n = blockIdx.y;
  const int nh = n * 8 + h;
  const int t = threadIdx.x;
  if (t < 64) {
    float s = 0.f;
#pragma unroll
    for (int c = 0; c < 8; c++) s += ssum[(((size_t)nh * 8 + c) << 6) + t];
    srow[t] = 1.0f / s;
  }
  __syncthreads();
  const float* pp = partial + ((size_t)nh << 15);
#pragma unroll
  for (int i = 0; i < 16; i++) {
    const int kvi = i * 256 + t;
    float v = 0.f;
#pragma unroll
    for (int c = 0; c < 8; c++) v += pp[((size_t)c << 12) + kvi];
    ctx_tile[kvi >> 6][kvi & 63] = (__bf16)(v * srow[kvi >> 6]);
  }
  __syncthreads();
  // mfuse phase: 4 c-subtiles of 128; wave covers 32 c each.
  const int lane = t & 63, wave = t >> 6;
  const int l15 = lane & 15, quad = lane >> 4;
#pragma unroll 1
  for (int ms = 0; ms < 4; ms++) {
    f32x4 acc[2][4];
#pragma unroll
    for (int i = 0; i < 2; i++)
#pragma unroll
      for (int j = 0; j < 4; j++) acc[i][j] = (f32x4){0.f, 0.f, 0.f, 0.f};
    const __bf16* Ap = WrB + (size_t)(ms * 128 + wave * 32 + l15) * 512 + h * 64 + quad * 8;
#pragma unroll
    for (int k0 = 0; k0 < 64; k0 += 32) {
      bf16x8 av[2];
#pragma unroll
      for (int i = 0; i < 2; i++) av[i] = *(const bf16x8*)(Ap + i * 16 * 512 + k0);
#pragma unroll
      for (int j = 0; j < 4; j++) {
        bf16x8 bv = *(const bf16x8*)(&ctx_tile[j * 16 + l15][quad * 8 + k0]);
#pragma unroll
        for (int i = 0; i < 2; i++)
          acc[i][j] = __builtin_amdgcn_mfma_f32_16x16x32_bf16(av[i], bv, acc[i][j], 0, 0, 0);
      }
    }
#pragma unroll
    for (int i = 0; i < 2; i++)
#pragma unroll
      for (int j = 0; j < 4; j++)
#pragma unroll
        for (int r = 0; r < 4; r++) {
          const int c = ms * 128 + wave * 32 + i * 16 + quad * 4 + r;
          const int col = h * 64 + j * 16 + l15;
          Mf[((size_t)n * 512 + c) * 512 + col] = (__bf16)acc[i][j][r];
        }
  }
}

// ---------------------------------------------------------------------------
extern "C" void kernel_launch(void* const* d_in, const int* in_sizes, int n_in,
                              void* d_out, int out_size, void* d_ws, size_t ws_size,
                              hipStream_t stream) {
  (void)in_sizes; (void)n_in; (void)out_size; (void)ws_size;
  const float* x  = (const float*)d_in[0];
  const float* Wk = (const float*)d_in[1];
  const float* bk = (const float*)d_in[2];
  const float* Wq = (const float*)d_in[3];
  const float* bq = (const float*)d_in[4];
  const float* Wv = (const float*)d_in[5];
  const float* bv = (const float*)d_in[6];
  const float* Wr = (const float*)d_in[7];
  const float* br = (const float*)d_in[8];
  float* out = (float*)d_out;

  // Workspace layout (256 MiB):
  //   [0,64M)    xT bf16 [8][8192][512]   (dead after gemm_kvq; region reused:)
  //     [0,8M)     ctx partials fp32
  //     [20M,24M)  Mf bf16 [8][512][512]
  //   [64M,192M) kv bf16 [8][1024][8192]
  //   [192M,256M) qT bf16 [8][8192][512]
  // Weights/ssum live in the tail 4 MiB of d_out (dead before gemm_out runs).
  char* ws = (char*)d_ws;
  __bf16* xT      = (__bf16*)ws;
  float*  partial = (float*)ws;
  __bf16* Mf      = (__bf16*)(ws + (20ull << 20));
  __bf16* kv      = (__bf16*)(ws + (64ull << 20));
  __bf16* qT      = (__bf16*)(ws + (192ull << 20));

  char* scr = (char*)d_out + (124ull << 20);
  __bf16* WkvB = (__bf16*)scr;                         // 1 MiB
  __bf16* WqB  = (__bf16*)(scr + (1ull << 20));        // 0.5 MiB
  __bf16* WrB  = (__bf16*)(scr + (1536ull << 10));     // 0.5 MiB
  float*  bkv  = (float*)(scr + (2ull << 20));         // 4 KiB
  float*  ssum = (float*)(scr + (2ull << 20) + 65536); // 128 KiB

  prep_x_kernel<<<dim3(128, 4, 8), 256, 0, stream>>>(x, xT);
  prep_w_kernel<<<dim3(1024), 256, 0, stream>>>(Wk, Wq, Wv, Wr, bk, bv, WkvB, WqB, WrB, bkv);
  gemm_kvq_kernel<<<dim3(64, 12, 8), 256, 0, stream>>>(WkvB, WqB, xT, bkv, bq, kv, qT);
  ctx_kernel<<<dim3(8, 8, 8), 256, 0, stream>>>(kv, partial, ssum);
  ctx_finish_kernel<<<dim3(8, 8), 256, 0, stream>>>(partial, ssum, WrB, Mf);
  gemm_out_kernel<<<dim3(64, 4, 8), 256, 0, stream>>>(Mf, qT, br, x, out);
}

// Round 4
// 503.107 us; speedup vs baseline: 1.0242x; 1.0029x over previous
//
#include <hip/hip_runtime.h>
#include <hip/hip_bf16.h>
#include <cstdint>

// Fixed problem shape (EfficientAttention): n=8, C=512, W=8192, H=8, hk=hv=64
#define NB 8
#define CD 512
#define WD 8192
#define NH 8

typedef __bf16 bf16x8 __attribute__((ext_vector_type(8)));
typedef float  f32x4  __attribute__((ext_vector_type(4)));
typedef float  f32x16 __attribute__((ext_vector_type(16)));

// async global->LDS, 16B per lane (wave-uniform base + lane*16 dest).
__device__ __forceinline__ void gload_lds16(const __bf16* g, __bf16* l) {
  __builtin_amdgcn_global_load_lds((const __attribute__((address_space(1))) void*)g,
                                   (__attribute__((address_space(3))) void*)l,
                                   16, 0, 0);
}

// ---------------------------------------------------------------------------
// prep_x: x[n][512][8192] fp32 -> xT[n][8192][512] bf16.
// Round-4: fully vectorized. float4 (16B) reads, [64][65] LDS tile (odd pad:
// transposed gather banks = (8*c8 + e + w) % 32 -> exactly 2-way, free),
// bf16x8 (16B) writes in 128B row segments.
// ---------------------------------------------------------------------------
__global__ void __launch_bounds__(256) prep_x_kernel(const float* __restrict__ x,
                                                     __bf16* __restrict__ xT) {
  __shared__ float tile[64][65];
  const int n = blockIdx.z, cb = blockIdx.y * 64, wb = blockIdx.x * 64;
  const int t = threadIdx.x;
  const int lr = t >> 4;          // 0..15 c-row within group
  const int lw4 = (t & 15) * 4;   // w offset (float4)
  const float* xp = x + ((size_t)n * CD + cb) * WD + wb;
#pragma unroll
  for (int it = 0; it < 4; it++) {
    const int cc = it * 16 + lr;
    const f32x4 v = *(const f32x4*)(xp + (size_t)cc * WD + lw4);
    tile[cc][lw4 + 0] = v[0];
    tile[cc][lw4 + 1] = v[1];
    tile[cc][lw4 + 2] = v[2];
    tile[cc][lw4 + 3] = v[3];
  }
  __syncthreads();
  const int c8 = (t & 7) * 8;
  __bf16* op = xT + ((size_t)n * WD + wb) * CD + cb;
#pragma unroll
  for (int it = 0; it < 2; it++) {
    const int ww = it * 32 + (t >> 3);
    bf16x8 o;
#pragma unroll
    for (int e = 0; e < 8; e++) o[e] = (__bf16)tile[c8 + e][ww];
    *(bf16x8*)(op + (size_t)ww * CD + c8) = o;
  }
}

// ---------------------------------------------------------------------------
// prep_w: convert weights to bf16; pack bk|bv into bkv
// ---------------------------------------------------------------------------
__global__ void __launch_bounds__(256) prep_w_kernel(const float* __restrict__ Wk,
                                                     const float* __restrict__ Wq,
                                                     const float* __restrict__ Wv,
                                                     const float* __restrict__ Wr,
                                                     const float* __restrict__ bk,
                                                     const float* __restrict__ bv,
                                                     __bf16* __restrict__ WkvB,
                                                     __bf16* __restrict__ WqB,
                                                     __bf16* __restrict__ WrB,
                                                     float* __restrict__ bkv) {
  const int gid = blockIdx.x * 256 + threadIdx.x;  // 0..262143
  WkvB[gid]          = (__bf16)Wk[gid];
  WkvB[262144 + gid] = (__bf16)Wv[gid];
  WqB[gid]           = (__bf16)Wq[gid];
  WrB[gid]           = (__bf16)Wr[gid];
  if (gid < 512)       bkv[gid] = bk[gid];
  else if (gid < 1024) bkv[gid] = bv[gid - 512];
}

// ---------------------------------------------------------------------------
// Shared LDS staging: 2048 16B chunks (A:[0,1024) B:[1024,2048)).
// Chunk (row r, kgroup g) of current BK=64 slab -> slot r*8 + (g^(r&7)).
// ---------------------------------------------------------------------------
#define STAGE_SLAB(Ak, Bk, lds, t)                                          \
  _Pragma("unroll") for (int rnd = 0; rnd < 8; rnd++) {                     \
    const int c = rnd * 256 + (t);                                          \
    const int cc = c & 1023;                                                \
    const int r = cc >> 3;                                                  \
    const int g = (cc & 7) ^ (r & 7);                                       \
    const __bf16* src = ((c >> 10) ? (Bk) : (Ak)) + (size_t)r * 512 + g * 8;\
    gload_lds16(src, (lds) + (size_t)c * 8);                                \
  }

// 16x16x32 core (verified). A[m][k], BT[n][k], K=512, ld=512.
__device__ __forceinline__ void gemm_lds_core(const __bf16* __restrict__ A,
                                              const __bf16* __restrict__ B,
                                              f32x4 (&acc)[4][4], __bf16* lds) {
  const int t = threadIdx.x;
  const int lane = t & 63, wave = t >> 6;
  const int l15 = lane & 15, quad = lane >> 4;
  const int wm = (wave >> 1) << 6, wn = (wave & 1) << 6;
#pragma unroll 1
  for (int kc = 0; kc < 8; kc++) {
    const __bf16* Ak = A + kc * 64;
    const __bf16* Bk = B + kc * 64;
    STAGE_SLAB(Ak, Bk, lds, t)
    __syncthreads();
#pragma unroll
    for (int k0 = 0; k0 < 2; k0++) {
      const int gk = k0 * 4 + quad;
      bf16x8 av[4], bv[4];
#pragma unroll
      for (int i = 0; i < 4; i++) {
        const int r = wm + i * 16 + l15;
        av[i] = *(const bf16x8*)(lds + (size_t)((r << 3) + (gk ^ (r & 7))) * 8);
      }
#pragma unroll
      for (int j = 0; j < 4; j++) {
        const int r = wn + j * 16 + l15;
        bv[j] = *(const bf16x8*)(lds + (size_t)(8192 + (r << 3) + (gk ^ (r & 7))) * 8);
      }
#pragma unroll
      for (int i = 0; i < 4; i++)
#pragma unroll
        for (int j = 0; j < 4; j++)
          acc[i][j] = __builtin_amdgcn_mfma_f32_16x16x32_bf16(av[i], bv[j], acc[i][j], 0, 0, 0);
    }
    __syncthreads();
  }
}

// 32x32x16 core: same staging/swizzle, half the MFMA instruction count.
// D: col=lane&31, row=(reg&3)+8*(reg>>2)+4*(lane>>5)  (m74/m101 verified).
__device__ __forceinline__ void gemm_lds_core32(const __bf16* __restrict__ A,
                                                const __bf16* __restrict__ B,
                                                f32x16 (&acc)[2][2], __bf16* lds) {
  const int t = threadIdx.x;
  const int lane = t & 63, wave = t >> 6;
  const int l31 = lane & 31, khalf = lane >> 5;
  const int wm = (wave >> 1) << 6, wn = (wave & 1) << 6;
#pragma unroll 1
  for (int kc = 0; kc < 8; kc++) {
    const __bf16* Ak = A + kc * 64;
    const __bf16* Bk = B + kc * 64;
    STAGE_SLAB(Ak, Bk, lds, t)
    __syncthreads();
#pragma unroll
    for (int kk = 0; kk < 4; kk++) {
      const int g = kk * 2 + khalf;
      bf16x8 av[2], bv[2];
#pragma unroll
      for (int i = 0; i < 2; i++) {
        const int r = wm + i * 32 + l31;
        av[i] = *(const bf16x8*)(lds + (size_t)((r << 3) + (g ^ (r & 7))) * 8);
      }
#pragma unroll
      for (int j = 0; j < 2; j++) {
        const int r = wn + j * 32 + l31;
        bv[j] = *(const bf16x8*)(lds + (size_t)(8192 + (r << 3) + (g ^ (r & 7))) * 8);
      }
#pragma unroll
      for (int i = 0; i < 2; i++)
#pragma unroll
        for (int j = 0; j < 2; j++)
          acc[i][j] = __builtin_amdgcn_mfma_f32_32x32x16_bf16(av[i], bv[j], acc[i][j], 0, 0, 0);
    }
    __syncthreads();
  }
}

// kv[n][1024][8192] bf16 : rows 0..511 = keys, 512..1023 = values (+bias)
__global__ void __launch_bounds__(256) gemm_kv_kernel(const __bf16* __restrict__ WkvB,
                                                      const __bf16* __restrict__ xT,
                                                      const float* __restrict__ bkv,
                                                      __bf16* __restrict__ kv) {
  __shared__ __bf16 lds[16384];
  const int n = blockIdx.z, m0 = blockIdx.y * 128, w0 = blockIdx.x * 128;
  f32x16 acc[2][2];
#pragma unroll
  for (int i = 0; i < 2; i++)
#pragma unroll
    for (int j = 0; j < 2; j++)
#pragma unroll
      for (int r = 0; r < 16; r++) acc[i][j][r] = 0.f;
  gemm_lds_core32(WkvB + (size_t)m0 * 512, xT + ((size_t)n * WD + w0) * 512, acc, lds);
  const int t = threadIdx.x, lane = t & 63, wave = t >> 6;
  const int l31 = lane & 31, khalf = lane >> 5;
  const int wm = (wave >> 1) << 6, wn = (wave & 1) << 6;
  __bf16* outp = kv + (size_t)n * 1024 * WD + w0 + wn + l31;
#pragma unroll
  for (int i = 0; i < 2; i++)
#pragma unroll
    for (int reg = 0; reg < 16; reg++) {
      const int row = (reg & 3) + 8 * (reg >> 2) + 4 * khalf;
      const int m = m0 + wm + i * 32 + row;
      const float bias = bkv[m];
      __bf16* rp = outp + (size_t)m * WD;
#pragma unroll
      for (int j = 0; j < 2; j++) rp[j * 32] = (__bf16)(acc[i][j][reg] + bias);
    }
}

// gemm_qT + fused Q-softmax epilogue.
// qT[n][8192][512] bf16 : queries transposed (w-major), softmaxed per head.
__global__ void __launch_bounds__(256) gemm_qT_kernel(const __bf16* __restrict__ xT,
                                                      const __bf16* __restrict__ WqB,
                                                      const float* __restrict__ bq,
                                                      __bf16* __restrict__ qT) {
  __shared__ __bf16 lds[16384];
  const int n = blockIdx.z, w0 = blockIdx.x * 128, q0 = blockIdx.y * 128;
  f32x4 acc[4][4];
#pragma unroll
  for (int i = 0; i < 4; i++)
#pragma unroll
    for (int j = 0; j < 4; j++) acc[i][j] = (f32x4){0.f, 0.f, 0.f, 0.f};
  gemm_lds_core(xT + ((size_t)n * WD + w0) * 512, WqB + (size_t)q0 * 512, acc, lds);
  const int t = threadIdx.x, lane = t & 63, wave = t >> 6;
  const int l15 = lane & 15, quad = lane >> 4;
  const int wm = (wave >> 1) << 6, wn = (wave & 1) << 6;
  float bqv[4];
#pragma unroll
  for (int j = 0; j < 4; j++) bqv[j] = bq[q0 + wn + j * 16 + l15];
#pragma unroll
  for (int i = 0; i < 4; i++)
#pragma unroll
    for (int r = 0; r < 4; r++) {
      float e[4];
      float s = 0.f;
#pragma unroll
      for (int j = 0; j < 4; j++) {
        e[j] = __expf(acc[i][j][r] + bqv[j]);
        s += e[j];
      }
      s += __shfl_xor(s, 1);
      s += __shfl_xor(s, 2);
      s += __shfl_xor(s, 4);
      s += __shfl_xor(s, 8);
      const float inv = 1.0f / s;
      const int w = w0 + wm + i * 16 + quad * 4 + r;
      __bf16* rp = qT + ((size_t)n * WD + w) * 512 + q0 + wn + l15;
#pragma unroll
      for (int j = 0; j < 4; j++) rp[j * 16] = (__bf16)(e[j] * inv);
    }
}

// final: out[n][512][8192] fp32 = Mf[n] (512x512) @ Qsm + br + x
__global__ void __launch_bounds__(256) gemm_out_kernel(const __bf16* __restrict__ Mf,
                                                       const __bf16* __restrict__ qT,
                                                       const float* __restrict__ br,
                                                       const float* __restrict__ x,
                                                       float* __restrict__ out) {
  __shared__ __bf16 lds[16384];
  const int n = blockIdx.z, c0 = blockIdx.y * 128, w0 = blockIdx.x * 128;
  f32x16 acc[2][2];
#pragma unroll
  for (int i = 0; i < 2; i++)
#pragma unroll
    for (int j = 0; j < 2; j++)
#pragma unroll
      for (int r = 0; r < 16; r++) acc[i][j][r] = 0.f;
  gemm_lds_core32(Mf + ((size_t)n * 512 + c0) * 512, qT + ((size_t)n * WD + w0) * 512, acc, lds);
  const int t = threadIdx.x, lane = t & 63, wave = t >> 6;
  const int l31 = lane & 31, khalf = lane >> 5;
  const int wm = (wave >> 1) << 6, wn = (wave & 1) << 6;
#pragma unroll
  for (int i = 0; i < 2; i++)
#pragma unroll
    for (int reg = 0; reg < 16; reg++) {
      const int row = (reg & 3) + 8 * (reg >> 2) + 4 * khalf;
      const int c = c0 + wm + i * 32 + row;
      const float bias = br[c];
      const size_t base = ((size_t)n * CD + c) * WD + w0 + wn + l31;
#pragma unroll
      for (int j = 0; j < 2; j++)
        out[base + j * 32] = acc[i][j][reg] + bias + x[base + j * 32];
    }
}

// ---------------------------------------------------------------------------
// ctx: partial[n][h][chunk][64][64] = sum_{w in chunk} exp(K[k,w]) * V[v,w]
// (unnormalized; exp is overflow-safe since |keys| <~ 3). Also emits per-row
// partial exp-sums ssum[n][h][chunk][64] via quad shuffle reduce.
// ---------------------------------------------------------------------------
__global__ void __launch_bounds__(256) ctx_kernel(const __bf16* __restrict__ kv,
                                                  float* __restrict__ partial,
                                                  float* __restrict__ ssum) {
  const int chunk = blockIdx.x, h = blockIdx.y, n = blockIdx.z;
  const int t = threadIdx.x, lane = t & 63, wave = t >> 6;
  const int l15 = lane & 15, quad = lane >> 4;
  const int krow = h * 64 + wave * 16 + l15;  // key channel (A row)
  const __bf16* Kp = kv + ((size_t)n * 1024 + krow) * WD + chunk * 1024 + quad * 8;
  const __bf16* Vp = kv + ((size_t)n * 1024 + 512 + h * 64 + l15) * WD + chunk * 1024 + quad * 8;
  f32x4 acc[4];
#pragma unroll
  for (int j = 0; j < 4; j++) acc[j] = (f32x4){0.f, 0.f, 0.f, 0.f};
  float esum = 0.f;
  for (int s = 0; s < 32; s++) {
    bf16x8 kraw = *(const bf16x8*)(Kp + s * 32);
    bf16x8 af;
#pragma unroll
    for (int e = 0; e < 8; e++) {
      const float ev = __expf((float)kraw[e]);
      esum += ev;
      af[e] = (__bf16)ev;
    }
#pragma unroll
    for (int j = 0; j < 4; j++) {
      bf16x8 bv = *(const bf16x8*)(Vp + (size_t)(j * 16) * WD + s * 32);
      acc[j] = __builtin_amdgcn_mfma_f32_16x16x32_bf16(af, bv, acc[j], 0, 0, 0);
    }
  }
  // reduce esum across the 4 quads sharing l15 (lanes differ in bits 4,5)
  esum += __shfl_xor(esum, 16);
  esum += __shfl_xor(esum, 32);
  float* pp = partial + (((size_t)(n * 8 + h) * 8 + chunk) << 12);
#pragma unroll
  for (int j = 0; j < 4; j++)
#pragma unroll
    for (int r = 0; r < 4; r++) {
      const int kr = wave * 16 + quad * 4 + r;
      const int vc = j * 16 + l15;
      pp[kr * 64 + vc] = acc[j][r];
    }
  if (lane < 16)
    ssum[(((size_t)(n * 8 + h) * 8 + chunk) << 6) + wave * 16 + l15] = esum;
}

// ---------------------------------------------------------------------------
// ctx_finish: merged ctx_reduce + mfuse. One block per (h,n).
// Phase 1: sum 8 chunk partials, normalize -> LDS ctx tile [64][72] bf16.
// Phase 2: Mf[n][c][h*64+k] = sum_v Wr[c][h*64+v] * ctx[k][v], B from LDS.
// ---------------------------------------------------------------------------
__global__ void __launch_bounds__(256) ctx_finish_kernel(const float* __restrict__ partial,
                                                         const float* __restrict__ ssum,
                                                         const __bf16* __restrict__ WrB,
                                                         __bf16* __restrict__ Mf) {
  __shared__ __bf16 ctx_tile[64][72];
  __shared__ float srow[64];
  const int h = blockIdx.x, n = blockIdx.y;
  const int nh = n * 8 + h;
  const int t = threadIdx.x;
  if (t < 64) {
    float s = 0.f;
#pragma unroll
    for (int c = 0; c < 8; c++) s += ssum[(((size_t)nh * 8 + c) << 6) + t];
    srow[t] = 1.0f / s;
  }
  __syncthreads();
  const float* pp = partial + ((size_t)nh << 15);
#pragma unroll
  for (int i = 0; i < 16; i++) {
    const int kvi = i * 256 + t;
    float v = 0.f;
#pragma unroll
    for (int c = 0; c < 8; c++) v += pp[((size_t)c << 12) + kvi];
    ctx_tile[kvi >> 6][kvi & 63] = (__bf16)(v * srow[kvi >> 6]);
  }
  __syncthreads();
  // mfuse phase: 4 c-subtiles of 128; wave covers 32 c each.
  const int lane = t & 63, wave = t >> 6;
  const int l15 = lane & 15, quad = lane >> 4;
#pragma unroll 1
  for (int ms = 0; ms < 4; ms++) {
    f32x4 acc[2][4];
#pragma unroll
    for (int i = 0; i < 2; i++)
#pragma unroll
      for (int j = 0; j < 4; j++) acc[i][j] = (f32x4){0.f, 0.f, 0.f, 0.f};
    const __bf16* Ap = WrB + (size_t)(ms * 128 + wave * 32 + l15) * 512 + h * 64 + quad * 8;
#pragma unroll
    for (int k0 = 0; k0 < 64; k0 += 32) {
      bf16x8 av[2];
#pragma unroll
      for (int i = 0; i < 2; i++) av[i] = *(const bf16x8*)(Ap + i * 16 * 512 + k0);
#pragma unroll
      for (int j = 0; j < 4; j++) {
        bf16x8 bv = *(const bf16x8*)(&ctx_tile[j * 16 + l15][quad * 8 + k0]);
#pragma unroll
        for (int i = 0; i < 2; i++)
          acc[i][j] = __builtin_amdgcn_mfma_f32_16x16x32_bf16(av[i], bv, acc[i][j], 0, 0, 0);
      }
    }
#pragma unroll
    for (int i = 0; i < 2; i++)
#pragma unroll
      for (int j = 0; j < 4; j++)
#pragma unroll
        for (int r = 0; r < 4; r++) {
          const int c = ms * 128 + wave * 32 + i * 16 + quad * 4 + r;
          const int col = h * 64 + j * 16 + l15;
          Mf[((size_t)n * 512 + c) * 512 + col] = (__bf16)acc[i][j][r];
        }
  }
}

// ---------------------------------------------------------------------------
extern "C" void kernel_launch(void* const* d_in, const int* in_sizes, int n_in,
                              void* d_out, int out_size, void* d_ws, size_t ws_size,
                              hipStream_t stream) {
  (void)in_sizes; (void)n_in; (void)out_size; (void)ws_size;
  const float* x  = (const float*)d_in[0];
  const float* Wk = (const float*)d_in[1];
  const float* bk = (const float*)d_in[2];
  const float* Wq = (const float*)d_in[3];
  const float* bq = (const float*)d_in[4];
  const float* Wv = (const float*)d_in[5];
  const float* bv = (const float*)d_in[6];
  const float* Wr = (const float*)d_in[7];
  const float* br = (const float*)d_in[8];
  float* out = (float*)d_out;

  // Workspace layout (256 MiB):
  //   [0,64M)    xT bf16 [8][8192][512]   (dead after gemm_qT; region reused:)
  //     [0,8M)     ctx partials fp32
  //     [20M,24M)  Mf bf16 [8][512][512]
  //   [64M,192M) kv bf16 [8][1024][8192]
  //   [192M,256M) qT bf16 [8][8192][512]
  // Weights/ssum live in the tail 4 MiB of d_out (dead before gemm_out runs).
  char* ws = (char*)d_ws;
  __bf16* xT      = (__bf16*)ws;
  float*  partial = (float*)ws;
  __bf16* Mf      = (__bf16*)(ws + (20ull << 20));
  __bf16* kv      = (__bf16*)(ws + (64ull << 20));
  __bf16* qT      = (__bf16*)(ws + (192ull << 20));

  char* scr = (char*)d_out + (124ull << 20);
  __bf16* WkvB = (__bf16*)scr;                         // 1 MiB
  __bf16* WqB  = (__bf16*)(scr + (1ull << 20));        // 0.5 MiB
  __bf16* WrB  = (__bf16*)(scr + (1536ull << 10));     // 0.5 MiB
  float*  bkv  = (float*)(scr + (2ull << 20));         // 4 KiB
  float*  ssum = (float*)(scr + (2ull << 20) + 65536); // 128 KiB

  prep_x_kernel<<<dim3(128, 8, 8), 256, 0, stream>>>(x, xT);
  prep_w_kernel<<<dim3(1024), 256, 0, stream>>>(Wk, Wq, Wv, Wr, bk, bv, WkvB, WqB, WrB, bkv);
  gemm_kv_kernel<<<dim3(64, 8, 8), 256, 0, stream>>>(WkvB, xT, bkv, kv);
  gemm_qT_kernel<<<dim3(64, 4, 8), 256, 0, stream>>>(xT, WqB, bq, qT);
  ctx_kernel<<<dim3(8, 8, 8), 256, 0, stream>>>(kv, partial, ssum);
  ctx_finish_kernel<<<dim3(8, 8), 256, 0, stream>>>(partial, ssum, WrB, Mf);
  gemm_out_kernel<<<dim3(64, 4, 8), 256, 0, stream>>>(Mf, qT, br, x, out);
}

// Round 5
// 481.226 us; speedup vs baseline: 1.0708x; 1.0455x over previous
//
#include <hip/hip_runtime.h>
#include <hip/hip_bf16.h>
#include <cstdint>

// Fixed problem shape (EfficientAttention): n=8, C=512, W=8192, H=8, hk=hv=64
#define NB 8
#define CD 512
#define WD 8192
#define NH 8

typedef __bf16 bf16x8 __attribute__((ext_vector_type(8)));
typedef float  f32x4  __attribute__((ext_vector_type(4)));
typedef float  f32x16 __attribute__((ext_vector_type(16)));

// async global->LDS, 16B per lane (wave-uniform base + lane*16 dest).
__device__ __forceinline__ void gload_lds16(const __bf16* g, __bf16* l) {
  __builtin_amdgcn_global_load_lds((const __attribute__((address_space(1))) void*)g,
                                   (__attribute__((address_space(3))) void*)l,
                                   16, 0, 0);
}

// ---------------------------------------------------------------------------
// prep_x: x[n][512][8192] fp32 -> xT[n][8192][512] bf16 (vectorized both sides)
// ---------------------------------------------------------------------------
__global__ void __launch_bounds__(256) prep_x_kernel(const float* __restrict__ x,
                                                     __bf16* __restrict__ xT) {
  __shared__ float tile[64][65];
  const int n = blockIdx.z, cb = blockIdx.y * 64, wb = blockIdx.x * 64;
  const int t = threadIdx.x;
  const int lr = t >> 4;          // 0..15 c-row within group
  const int lw4 = (t & 15) * 4;   // w offset (float4)
  const float* xp = x + ((size_t)n * CD + cb) * WD + wb;
#pragma unroll
  for (int it = 0; it < 4; it++) {
    const int cc = it * 16 + lr;
    const f32x4 v = *(const f32x4*)(xp + (size_t)cc * WD + lw4);
    tile[cc][lw4 + 0] = v[0];
    tile[cc][lw4 + 1] = v[1];
    tile[cc][lw4 + 2] = v[2];
    tile[cc][lw4 + 3] = v[3];
  }
  __syncthreads();
  const int c8 = (t & 7) * 8;
  __bf16* op = xT + ((size_t)n * WD + wb) * CD + cb;
#pragma unroll
  for (int it = 0; it < 2; it++) {
    const int ww = it * 32 + (t >> 3);
    bf16x8 o;
#pragma unroll
    for (int e = 0; e < 8; e++) o[e] = (__bf16)tile[c8 + e][ww];
    *(bf16x8*)(op + (size_t)ww * CD + c8) = o;
  }
}

// ---------------------------------------------------------------------------
// prep_w: weights -> bf16. WkvB is packed HEAD-MAJOR: for head h, rows
// [h*128, h*128+64) = Wk rows h*64..h*64+63, rows [h*128+64, h*128+128) =
// Wv rows h*64..h*64+63. bkv packed to match.
// ---------------------------------------------------------------------------
__global__ void __launch_bounds__(256) prep_w_kernel(const float* __restrict__ Wk,
                                                     const float* __restrict__ Wq,
                                                     const float* __restrict__ Wv,
                                                     const float* __restrict__ Wr,
                                                     const float* __restrict__ bk,
                                                     const float* __restrict__ bv,
                                                     __bf16* __restrict__ WkvB,
                                                     __bf16* __restrict__ WqB,
                                                     __bf16* __restrict__ WrB,
                                                     float* __restrict__ bkv) {
  const int gid = blockIdx.x * 256 + threadIdx.x;  // 0..262143
  const int r = gid >> 9;        // source row 0..511
  const int cpos = gid & 511;
  const int h = r >> 6, wi = r & 63;
  WkvB[((size_t)(h * 128 + wi) << 9) + cpos]      = (__bf16)Wk[gid];
  WkvB[((size_t)(h * 128 + 64 + wi) << 9) + cpos] = (__bf16)Wv[gid];
  WqB[gid] = (__bf16)Wq[gid];
  WrB[gid] = (__bf16)Wr[gid];
  if (gid < 512) {
    bkv[(gid >> 6) * 128 + (gid & 63)] = bk[gid];
  } else if (gid < 1024) {
    const int rr = gid - 512;
    bkv[(rr >> 6) * 128 + 64 + (rr & 63)] = bv[rr];
  }
}

// ---------------------------------------------------------------------------
// Shared LDS staging: 2048 16B chunks (A:[0,1024) B:[1024,2048)).
// Chunk (row r, kgroup g) of current BK=64 slab -> slot r*8 + (g^(r&7)).
// ---------------------------------------------------------------------------
#define STAGE_SLAB(Ak, Bk, lds, t)                                          \
  _Pragma("unroll") for (int rnd = 0; rnd < 8; rnd++) {                     \
    const int c = rnd * 256 + (t);                                          \
    const int cc = c & 1023;                                                \
    const int r = cc >> 3;                                                  \
    const int g = (cc & 7) ^ (r & 7);                                       \
    const __bf16* src = ((c >> 10) ? (Bk) : (Ak)) + (size_t)r * 512 + g * 8;\
    gload_lds16(src, (lds) + (size_t)c * 8);                                \
  }

// 16x16x32 core (verified). A[m][k], BT[n][k], K=512, ld=512.
__device__ __forceinline__ void gemm_lds_core(const __bf16* __restrict__ A,
                                              const __bf16* __restrict__ B,
                                              f32x4 (&acc)[4][4], __bf16* lds) {
  const int t = threadIdx.x;
  const int lane = t & 63, wave = t >> 6;
  const int l15 = lane & 15, quad = lane >> 4;
  const int wm = (wave >> 1) << 6, wn = (wave & 1) << 6;
#pragma unroll 1
  for (int kc = 0; kc < 8; kc++) {
    const __bf16* Ak = A + kc * 64;
    const __bf16* Bk = B + kc * 64;
    STAGE_SLAB(Ak, Bk, lds, t)
    __syncthreads();
#pragma unroll
    for (int k0 = 0; k0 < 2; k0++) {
      const int gk = k0 * 4 + quad;
      bf16x8 av[4], bv[4];
#pragma unroll
      for (int i = 0; i < 4; i++) {
        const int r = wm + i * 16 + l15;
        av[i] = *(const bf16x8*)(lds + (size_t)((r << 3) + (gk ^ (r & 7))) * 8);
      }
#pragma unroll
      for (int j = 0; j < 4; j++) {
        const int r = wn + j * 16 + l15;
        bv[j] = *(const bf16x8*)(lds + (size_t)(8192 + (r << 3) + (gk ^ (r & 7))) * 8);
      }
#pragma unroll
      for (int i = 0; i < 4; i++)
#pragma unroll
        for (int j = 0; j < 4; j++)
          acc[i][j] = __builtin_amdgcn_mfma_f32_16x16x32_bf16(av[i], bv[j], acc[i][j], 0, 0, 0);
    }
    __syncthreads();
  }
}

// 32x32x16 core: same staging/swizzle, half the MFMA instruction count.
// D: col=lane&31, row=(reg&3)+8*(reg>>2)+4*(lane>>5)  (m74/m101 verified).
__device__ __forceinline__ void gemm_lds_core32(const __bf16* __restrict__ A,
                                                const __bf16* __restrict__ B,
                                                f32x16 (&acc)[2][2], __bf16* lds) {
  const int t = threadIdx.x;
  const int lane = t & 63, wave = t >> 6;
  const int l31 = lane & 31, khalf = lane >> 5;
  const int wm = (wave >> 1) << 6, wn = (wave & 1) << 6;
#pragma unroll 1
  for (int kc = 0; kc < 8; kc++) {
    const __bf16* Ak = A + kc * 64;
    const __bf16* Bk = B + kc * 64;
    STAGE_SLAB(Ak, Bk, lds, t)
    __syncthreads();
#pragma unroll
    for (int kk = 0; kk < 4; kk++) {
      const int g = kk * 2 + khalf;
      bf16x8 av[2], bv[2];
#pragma unroll
      for (int i = 0; i < 2; i++) {
        const int r = wm + i * 32 + l31;
        av[i] = *(const bf16x8*)(lds + (size_t)((r << 3) + (g ^ (r & 7))) * 8);
      }
#pragma unroll
      for (int j = 0; j < 2; j++) {
        const int r = wn + j * 32 + l31;
        bv[j] = *(const bf16x8*)(lds + (size_t)(8192 + (r << 3) + (g ^ (r & 7))) * 8);
      }
#pragma unroll
      for (int i = 0; i < 2; i++)
#pragma unroll
        for (int j = 0; j < 2; j++)
          acc[i][j] = __builtin_amdgcn_mfma_f32_32x32x16_bf16(av[i], bv[j], acc[i][j], 0, 0, 0);
    }
    __syncthreads();
  }
}

// ---------------------------------------------------------------------------
// gemm_kvctx: FUSED kv-GEMM + ctx. Block (w-chunk, head, n) computes the
// K[64][128] and V[64][128] tiles for head h / w-range (head-major WkvB),
// applies bias, exp's K — all in LDS (kv NEVER touches HBM) — then does the
// ctx contraction ctx[k][v] += sum_w expK[k][w]*V[v][w] (16x16x32 MFMA, A and
// B both w-major from LDS) and fp32-atomicAdds into ctx_accum[n][h][64][64].
// Row exp-sums via a ones-B-fragment MFMA -> atomicAdd ssum[n][h][64].
// LDS: core uses smem[0,16384); ctx tiles reuse smem: ek[64][136],
// vt[64][136] (pad 136: row stride 272B -> ~2-way banks on b128 reads).
// ---------------------------------------------------------------------------
#define LDE 136
__global__ void __launch_bounds__(256) gemm_kvctx_kernel(const __bf16* __restrict__ WkvB,
                                                         const __bf16* __restrict__ xT,
                                                         const float* __restrict__ bkv,
                                                         float* __restrict__ ctx_accum,
                                                         float* __restrict__ ssum) {
  __shared__ __bf16 smem[2 * 64 * LDE];  // 34816 B >= core's 32768 B
  const int n = blockIdx.z, h = blockIdx.y, w0 = blockIdx.x * 128;
  f32x16 acc[2][2];
#pragma unroll
  for (int i = 0; i < 2; i++)
#pragma unroll
    for (int j = 0; j < 2; j++)
#pragma unroll
      for (int r = 0; r < 16; r++) acc[i][j][r] = 0.f;
  gemm_lds_core32(WkvB + ((size_t)h * 128) * 512, xT + ((size_t)n * WD + w0) * 512, acc, smem);

  const int t = threadIdx.x, lane = t & 63, wave = t >> 6;
  const int l31 = lane & 31, khalf = lane >> 5;
  const int l15 = lane & 15, quad = lane >> 4;
  const int wm = (wave >> 1) << 6, wn = (wave & 1) << 6;
  __bf16* ek = smem;             // expK [64][LDE]
  __bf16* vt = smem + 64 * LDE;  // V    [64][LDE]
  const bool isK = (wm == 0);    // waves 0,1 hold K rows (m 0..63)
#pragma unroll
  for (int i = 0; i < 2; i++)
#pragma unroll
    for (int reg = 0; reg < 16; reg++) {
      const int row = (reg & 3) + 8 * (reg >> 2) + 4 * khalf;
      const int lr = i * 32 + row;       // 0..63 within ek/vt
      const float bias = bkv[h * 128 + wm + lr];
#pragma unroll
      for (int j = 0; j < 2; j++) {
        const int w = wn + j * 32 + l31;
        const float val = acc[i][j][reg] + bias;
        if (isK) ek[lr * LDE + w] = (__bf16)__expf(val);
        else     vt[lr * LDE + w] = (__bf16)val;
      }
    }
  __syncthreads();

  // ctx contraction: wave covers k-rows [wave*16, +16), all 64 v-cols, K=128.
  f32x4 cacc[4];
  f32x4 sacc = (f32x4){0.f, 0.f, 0.f, 0.f};
#pragma unroll
  for (int jj = 0; jj < 4; jj++) cacc[jj] = (f32x4){0.f, 0.f, 0.f, 0.f};
  bf16x8 ones;
#pragma unroll
  for (int e = 0; e < 8; e++) ones[e] = (__bf16)1.0f;
#pragma unroll
  for (int ks = 0; ks < 4; ks++) {
    const bf16x8 av = *(const bf16x8*)(ek + (wave * 16 + l15) * LDE + ks * 32 + quad * 8);
    sacc = __builtin_amdgcn_mfma_f32_16x16x32_bf16(av, ones, sacc, 0, 0, 0);
#pragma unroll
    for (int jj = 0; jj < 4; jj++) {
      const bf16x8 bvv = *(const bf16x8*)(vt + (jj * 16 + l15) * LDE + ks * 32 + quad * 8);
      cacc[jj] = __builtin_amdgcn_mfma_f32_16x16x32_bf16(av, bvv, cacc[jj], 0, 0, 0);
    }
  }
  float* cp = ctx_accum + ((size_t)(n * 8 + h) << 12);
#pragma unroll
  for (int jj = 0; jj < 4; jj++)
#pragma unroll
    for (int r = 0; r < 4; r++) {
      const int k = wave * 16 + quad * 4 + r;
      atomicAdd(cp + k * 64 + jj * 16 + l15, cacc[jj][r]);
    }
  if (l15 == 0) {
#pragma unroll
    for (int r = 0; r < 4; r++)
      atomicAdd(ssum + ((size_t)(n * 8 + h) << 6) + wave * 16 + quad * 4 + r, sacc[r]);
  }
}

// gemm_qT + fused Q-softmax epilogue.
// qT[n][8192][512] bf16 : queries transposed (w-major), softmaxed per head.
__global__ void __launch_bounds__(256) gemm_qT_kernel(const __bf16* __restrict__ xT,
                                                      const __bf16* __restrict__ WqB,
                                                      const float* __restrict__ bq,
                                                      __bf16* __restrict__ qT) {
  __shared__ __bf16 lds[16384];
  const int n = blockIdx.z, w0 = blockIdx.x * 128, q0 = blockIdx.y * 128;
  f32x4 acc[4][4];
#pragma unroll
  for (int i = 0; i < 4; i++)
#pragma unroll
    for (int j = 0; j < 4; j++) acc[i][j] = (f32x4){0.f, 0.f, 0.f, 0.f};
  gemm_lds_core(xT + ((size_t)n * WD + w0) * 512, WqB + (size_t)q0 * 512, acc, lds);
  const int t = threadIdx.x, lane = t & 63, wave = t >> 6;
  const int l15 = lane & 15, quad = lane >> 4;
  const int wm = (wave >> 1) << 6, wn = (wave & 1) << 6;
  float bqv[4];
#pragma unroll
  for (int j = 0; j < 4; j++) bqv[j] = bq[q0 + wn + j * 16 + l15];
#pragma unroll
  for (int i = 0; i < 4; i++)
#pragma unroll
    for (int r = 0; r < 4; r++) {
      float e[4];
      float s = 0.f;
#pragma unroll
      for (int j = 0; j < 4; j++) {
        e[j] = __expf(acc[i][j][r] + bqv[j]);
        s += e[j];
      }
      s += __shfl_xor(s, 1);
      s += __shfl_xor(s, 2);
      s += __shfl_xor(s, 4);
      s += __shfl_xor(s, 8);
      const float inv = 1.0f / s;
      const int w = w0 + wm + i * 16 + quad * 4 + r;
      __bf16* rp = qT + ((size_t)n * WD + w) * 512 + q0 + wn + l15;
#pragma unroll
      for (int j = 0; j < 4; j++) rp[j * 16] = (__bf16)(e[j] * inv);
    }
}

// final: out[n][512][8192] fp32 = Mf[n] (512x512) @ Qsm + br + x
__global__ void __launch_bounds__(256) gemm_out_kernel(const __bf16* __restrict__ Mf,
                                                       const __bf16* __restrict__ qT,
                                                       const float* __restrict__ br,
                                                       const float* __restrict__ x,
                                                       float* __restrict__ out) {
  __shared__ __bf16 lds[16384];
  const int n = blockIdx.z, c0 = blockIdx.y * 128, w0 = blockIdx.x * 128;
  f32x16 acc[2][2];
#pragma unroll
  for (int i = 0; i < 2; i++)
#pragma unroll
    for (int j = 0; j < 2; j++)
#pragma unroll
      for (int r = 0; r < 16; r++) acc[i][j][r] = 0.f;
  gemm_lds_core32(Mf + ((size_t)n * 512 + c0) * 512, qT + ((size_t)n * WD + w0) * 512, acc, lds);
  const int t = threadIdx.x, lane = t & 63, wave = t >> 6;
  const int l31 = lane & 31, khalf = lane >> 5;
  const int wm = (wave >> 1) << 6, wn = (wave & 1) << 6;
#pragma unroll
  for (int i = 0; i < 2; i++)
#pragma unroll
    for (int reg = 0; reg < 16; reg++) {
      const int row = (reg & 3) + 8 * (reg >> 2) + 4 * khalf;
      const int c = c0 + wm + i * 32 + row;
      const float bias = br[c];
      const size_t base = ((size_t)n * CD + c) * WD + w0 + wn + l31;
#pragma unroll
      for (int j = 0; j < 2; j++)
        out[base + j * 32] = acc[i][j][reg] + bias + x[base + j * 32];
    }
}

// ---------------------------------------------------------------------------
// ctx_finish: normalize ctx_accum rows by ssum -> LDS bf16 tile, then
// Mf[n][c][h*64+k] = sum_v Wr[c][h*64+v] * ctx[k][v]. One block per (h,n).
// ---------------------------------------------------------------------------
__global__ void __launch_bounds__(256) ctx_finish_kernel(const float* __restrict__ ctx_accum,
                                                         const float* __restrict__ ssum,
                                                         const __bf16* __restrict__ WrB,
                                                         __bf16* __restrict__ Mf) {
  __shared__ __bf16 ctx_tile[64][72];
  __shared__ float srow[64];
  const int h = blockIdx.x, n = blockIdx.y;
  const int nh = n * 8 + h;
  const int t = threadIdx.x;
  if (t < 64) srow[t] = 1.0f / ssum[((size_t)nh << 6) + t];
  __syncthreads();
  const float* cp = ctx_accum + ((size_t)nh << 12);
#pragma unroll
  for (int i = 0; i < 16; i++) {
    const int kvi = i * 256 + t;
    ctx_tile[kvi >> 6][kvi & 63] = (__bf16)(cp[kvi] * srow[kvi >> 6]);
  }
  __syncthreads();
  // mfuse phase: 4 c-subtiles of 128; wave covers 32 c each.
  const int lane = t & 63, wave = t >> 6;
  const int l15 = lane & 15, quad = lane >> 4;
#pragma unroll 1
  for (int ms = 0; ms < 4; ms++) {
    f32x4 acc[2][4];
#pragma unroll
    for (int i = 0; i < 2; i++)
#pragma unroll
      for (int j = 0; j < 4; j++) acc[i][j] = (f32x4){0.f, 0.f, 0.f, 0.f};
    const __bf16* Ap = WrB + (size_t)(ms * 128 + wave * 32 + l15) * 512 + h * 64 + quad * 8;
#pragma unroll
    for (int k0 = 0; k0 < 64; k0 += 32) {
      bf16x8 av[2];
#pragma unroll
      for (int i = 0; i < 2; i++) av[i] = *(const bf16x8*)(Ap + i * 16 * 512 + k0);
#pragma unroll
      for (int j = 0; j < 4; j++) {
        bf16x8 bv = *(const bf16x8*)(&ctx_tile[j * 16 + l15][quad * 8 + k0]);
#pragma unroll
        for (int i = 0; i < 2; i++)
          acc[i][j] = __builtin_amdgcn_mfma_f32_16x16x32_bf16(av[i], bv, acc[i][j], 0, 0, 0);
      }
    }
#pragma unroll
    for (int i = 0; i < 2; i++)
#pragma unroll
      for (int j = 0; j < 4; j++)
#pragma unroll
        for (int r = 0; r < 4; r++) {
          const int c = ms * 128 + wave * 32 + i * 16 + quad * 4 + r;
          const int col = h * 64 + j * 16 + l15;
          Mf[((size_t)n * 512 + c) * 512 + col] = (__bf16)acc[i][j][r];
        }
  }
}

// ---------------------------------------------------------------------------
extern "C" void kernel_launch(void* const* d_in, const int* in_sizes, int n_in,
                              void* d_out, int out_size, void* d_ws, size_t ws_size,
                              hipStream_t stream) {
  (void)in_sizes; (void)n_in; (void)out_size; (void)ws_size;
  const float* x  = (const float*)d_in[0];
  const float* Wk = (const float*)d_in[1];
  const float* bk = (const float*)d_in[2];
  const float* Wq = (const float*)d_in[3];
  const float* bq = (const float*)d_in[4];
  const float* Wv = (const float*)d_in[5];
  const float* bv = (const float*)d_in[6];
  const float* Wr = (const float*)d_in[7];
  const float* br = (const float*)d_in[8];
  float* out = (float*)d_out;

  // Workspace layout (256 MiB):
  //   [0,64M)    xT bf16 [8][8192][512]
  //   [20M,24M)  (unused gap kept for clarity)
  //   [64M,68M)  Mf bf16 [8][512][512]
  //   [192M,256M) qT bf16 [8][8192][512]
  // d_out tail 4 MiB (dead until gemm_out writes it): weights, bkv,
  // ctx_accum (1 MiB fp32), ssum (16 KiB fp32). All consumed before gemm_out.
  char* ws = (char*)d_ws;
  __bf16* xT = (__bf16*)ws;
  __bf16* Mf = (__bf16*)(ws + (64ull << 20));
  __bf16* qT = (__bf16*)(ws + (192ull << 20));

  char* scr = (char*)d_out + (124ull << 20);
  __bf16* WkvB     = (__bf16*)scr;                          // 1 MiB
  __bf16* WqB      = (__bf16*)(scr + (1ull << 20));         // 0.5 MiB
  __bf16* WrB      = (__bf16*)(scr + (1536ull << 10));      // 0.5 MiB
  float*  bkv      = (float*)(scr + (2ull << 20));          // 4 KiB
  float*  ctx_accum = (float*)(scr + (2560ull << 10));      // 1 MiB
  float*  ssum     = (float*)(scr + (3584ull << 10));       // 16 KiB

  prep_x_kernel<<<dim3(128, 8, 8), 256, 0, stream>>>(x, xT);
  prep_w_kernel<<<dim3(1024), 256, 0, stream>>>(Wk, Wq, Wv, Wr, bk, bv, WkvB, WqB, WrB, bkv);
  hipMemsetAsync(ctx_accum, 0, (1ull << 20) + (16ull << 10), stream);
  gemm_kvctx_kernel<<<dim3(64, 8, 8), 256, 0, stream>>>(WkvB, xT, bkv, ctx_accum, ssum);
  gemm_qT_kernel<<<dim3(64, 4, 8), 256, 0, stream>>>(xT, WqB, bq, qT);
  ctx_finish_kernel<<<dim3(8, 8), 256, 0, stream>>>(ctx_accum, ssum, WrB, Mf);
  gemm_out_kernel<<<dim3(64, 4, 8), 256, 0, stream>>>(Mf, qT, br, x, out);
}